// Round 1
// baseline (306.695 us; speedup 1.0000x reference)
//
#include <hip/hip_runtime.h>
#include <hip/hip_bf16.h>

typedef __bf16 bf16;
typedef __bf16 bf16x8 __attribute__((ext_vector_type(8)));
typedef float  f32x4  __attribute__((ext_vector_type(4)));

#define LOG2E        1.4426950408889634f
#define QSCALE_LOG2E 0.18033688011112043f   /* log2(e)/8 */

// ---------------------------------------------------------------------------
// LDS staging helpers: [128 rows][64 k] bf16 tile, 128B rows, 16B chunks
// XOR-swizzled: chunk' = chunk ^ (row & 7). Write/read use the same involution.
// ---------------------------------------------------------------------------
__device__ __forceinline__ void stage_f32_tile(const float* __restrict__ src, int ld,
                                               char* dst, int tid) {
  #pragma unroll
  for (int t = 0; t < 8; ++t) {
    int c8  = tid + t * 256;          // 2048 8-byte units = 128 rows * 16
    int row = c8 >> 4;
    int h8  = c8 & 15;
    const f32x4 v = *reinterpret_cast<const f32x4*>(src + row * ld + h8 * 4);
    union { bf16 h[4]; unsigned long long u; } pk;
    pk.h[0] = (bf16)v[0]; pk.h[1] = (bf16)v[1];
    pk.h[2] = (bf16)v[2]; pk.h[3] = (bf16)v[3];
    int byte = (row << 7) + ((((h8 >> 1) ^ (row & 7)) << 4) | ((h8 & 1) << 3));
    *reinterpret_cast<unsigned long long*>(dst + byte) = pk.u;
  }
}

__device__ __forceinline__ void stage_bf16_tile(const bf16* __restrict__ src, int ld,
                                                char* dst, int tid) {
  #pragma unroll
  for (int t = 0; t < 4; ++t) {
    int c   = tid + t * 256;          // 1024 16-byte chunks = 128 rows * 8
    int row = c >> 3;
    int ck  = c & 7;
    const bf16x8 v = *reinterpret_cast<const bf16x8*>(src + row * ld + ck * 8);
    int byte = (row << 7) + (((ck ^ (row & 7)) << 4));
    *reinterpret_cast<bf16x8*>(dst + byte) = v;
  }
}

// ---------------------------------------------------------------------------
// Kernel 1: all 5 projection GEMMs. grid = 5 * 64 * 4 = 1280 blocks, 256 thr.
// C[8192x512] = A[8192x512] @ W[512x512]^T + b, scattered to per-head layouts:
//   g=0/1 -> Qws (n,h,l,128) cols 0-511 / 512-1023
//   g=2/3 -> Kws (n,h,s,128)
//   g=4   -> Vtws (n,h,64,s)   (transposed for PV B-fragments)
// ---------------------------------------------------------------------------
__global__ __launch_bounds__(256) void proj_gemm(
    const float* __restrict__ qc, const float* __restrict__ qp,
    const float* __restrict__ kc, const float* __restrict__ kp,
    const float* __restrict__ vin,
    const float* __restrict__ Wqc, const float* __restrict__ bqc,
    const float* __restrict__ Wqp, const float* __restrict__ bqp,
    const float* __restrict__ Wkc, const float* __restrict__ bkc,
    const float* __restrict__ Wkp, const float* __restrict__ bkp,
    const float* __restrict__ Wv,  const float* __restrict__ bv,
    bf16* __restrict__ Qws, bf16* __restrict__ Kws, bf16* __restrict__ Vtws) {
  __shared__ __align__(16) bf16 lA[128 * 64];
  __shared__ __align__(16) bf16 lB[128 * 64];
  char* lAb = (char*)lA;
  char* lBb = (char*)lB;

  const int bx = blockIdx.x;
  const int g  = bx >> 8;             // which of the 5 GEMMs
  const int mt = (bx & 255) >> 2;     // 64 M-tiles
  const int nt = bx & 3;              // 4 N-tiles

  const float *A, *W, *bias;
  if      (g == 0) { A = qc;  W = Wqc; bias = bqc; }
  else if (g == 1) { A = qp;  W = Wqp; bias = bqp; }
  else if (g == 2) { A = kc;  W = Wkc; bias = bkc; }
  else if (g == 3) { A = kp;  W = Wkp; bias = bkp; }
  else             { A = vin; W = Wv;  bias = bv;  }

  const int tid  = threadIdx.x;
  const int lane = tid & 63, wid = tid >> 6;
  const int wr = wid >> 1, wc = wid & 1;
  const int lrow = lane & 15, lgrp = lane >> 4;

  const float* Abase = A + (size_t)(mt * 128) * 512;
  const float* Wbase = W + (size_t)(nt * 128) * 512;

  const f32x4 fz = {0.f, 0.f, 0.f, 0.f};
  f32x4 acc[4][4];
  #pragma unroll
  for (int i = 0; i < 4; ++i)
    #pragma unroll
    for (int j = 0; j < 4; ++j) acc[i][j] = fz;

  for (int k0 = 0; k0 < 512; k0 += 64) {
    __syncthreads();
    stage_f32_tile(Abase + k0, 512, lAb, tid);
    stage_f32_tile(Wbase + k0, 512, lBb, tid);
    __syncthreads();
    #pragma unroll
    for (int kk = 0; kk < 2; ++kk) {
      bf16x8 af[4], bfr[4];
      #pragma unroll
      for (int mf = 0; mf < 4; ++mf) {
        int row  = wr * 64 + mf * 16 + lrow;
        int byte = (row << 7) + ((((kk << 2) | lgrp) ^ (row & 7)) << 4);
        af[mf] = *reinterpret_cast<const bf16x8*>(lAb + byte);
      }
      #pragma unroll
      for (int nf = 0; nf < 4; ++nf) {
        int row  = wc * 64 + nf * 16 + lrow;
        int byte = (row << 7) + ((((kk << 2) | lgrp) ^ (row & 7)) << 4);
        bfr[nf] = *reinterpret_cast<const bf16x8*>(lBb + byte);
      }
      #pragma unroll
      for (int mf = 0; mf < 4; ++mf)
        #pragma unroll
        for (int nf = 0; nf < 4; ++nf)
          acc[mf][nf] = __builtin_amdgcn_mfma_f32_16x16x32_bf16(
              af[mf], bfr[nf], acc[mf][nf], 0, 0, 0);
    }
  }

  float bcol[4];
  #pragma unroll
  for (int nf = 0; nf < 4; ++nf)
    bcol[nf] = bias[nt * 128 + wc * 64 + nf * 16 + lrow];

  #pragma unroll
  for (int mf = 0; mf < 4; ++mf) {
    #pragma unroll
    for (int nf = 0; nf < 4; ++nf) {
      #pragma unroll
      for (int r = 0; r < 4; ++r) {
        int grow = mt * 128 + wr * 64 + mf * 16 + lgrp * 4 + r;  // 0..8191
        int col  = nt * 128 + wc * 64 + nf * 16 + lrow;          // 0..511
        float vv = acc[mf][nf][r] + bcol[nf];
        bf16 hb  = (bf16)vv;
        int n = grow >> 10, tt = grow & 1023;
        if (g < 2) {
          int j = (g << 9) + col;     // 0..1023
          Qws[(size_t)((((n << 3) + (j >> 7)) << 10) | tt) * 128 + (j & 127)] = hb;
        } else if (g < 4) {
          int j = ((g - 2) << 9) + col;
          Kws[(size_t)((((n << 3) + (j >> 7)) << 10) | tt) * 128 + (j & 127)] = hb;
        } else {
          int h = col >> 6, d = col & 63;
          Vtws[(size_t)((((n << 3) + h) << 6) + d) * 1024 + tt] = hb;
        }
      }
    }
  }
}

// ---------------------------------------------------------------------------
// Kernel 2: flash attention. grid = 64 (n,h) * 16 q-tiles = 1024 blocks.
// 4 waves x 16 queries; K/V fragments direct from global (L2-resident);
// mask fp32 from HBM; online softmax base-2; P via per-wave LDS transpose.
// ---------------------------------------------------------------------------
__global__ __launch_bounds__(256) void attn_fwd(
    const bf16* __restrict__ Qws, const bf16* __restrict__ Kws,
    const bf16* __restrict__ Vtws, const float* __restrict__ mask,
    bf16* __restrict__ Ows) {
  __shared__ __align__(16) bf16 Pl[4][16][32];

  const int bx = blockIdx.x;
  const int nh = bx >> 4;
  const int qt = bx & 15;
  const int tid = threadIdx.x;
  const int lane = tid & 63, wid = tid >> 6;
  const int lrow = lane & 15, lgrp = lane >> 4;
  const int q0 = qt * 64 + wid * 16;

  // Q fragments (held for the whole loop)
  const bf16* Qb = Qws + ((size_t)(nh * 1024 + q0 + lrow)) * 128 + lgrp * 8;
  bf16x8 qf[4];
  #pragma unroll
  for (int kk = 0; kk < 4; ++kk)
    qf[kk] = *reinterpret_cast<const bf16x8*>(Qb + kk * 32);

  const bf16*  Kb = Kws  + ((size_t)(nh * 1024 + lrow)) * 128 + lgrp * 8;
  const bf16*  Vb = Vtws + ((size_t)(nh * 64 + lrow)) * 1024 + lgrp * 8;
  const float* Mb = mask + ((size_t)(nh * 1024 + q0 + lgrp * 4)) * 1024 + lrow;

  char* Pb = (char*)&Pl[wid][0][0];

  const f32x4 fz = {0.f, 0.f, 0.f, 0.f};
  f32x4 oacc[4];
  #pragma unroll
  for (int dt = 0; dt < 4; ++dt) oacc[dt] = fz;
  float m2[4], lsum[4];
  #pragma unroll
  for (int r = 0; r < 4; ++r) { m2[r] = -1e30f; lsum[r] = 0.f; }

  for (int s0 = 0; s0 < 1024; s0 += 32) {
    // --- QK^T: two 16-key column tiles ---
    f32x4 sc0 = fz, sc1 = fz;
    #pragma unroll
    for (int kk = 0; kk < 4; ++kk) {
      bf16x8 kf = *reinterpret_cast<const bf16x8*>(Kb + (size_t)s0 * 128 + kk * 32);
      sc0 = __builtin_amdgcn_mfma_f32_16x16x32_bf16(qf[kk], kf, sc0, 0, 0, 0);
    }
    #pragma unroll
    for (int kk = 0; kk < 4; ++kk) {
      bf16x8 kf = *reinterpret_cast<const bf16x8*>(Kb + (size_t)(s0 + 16) * 128 + kk * 32);
      sc1 = __builtin_amdgcn_mfma_f32_16x16x32_bf16(qf[kk], kf, sc1, 0, 0, 0);
    }

    // logits (base-2): a = s * log2e/8 + mask * log2e
    float p0[4], p1[4], tmax[4];
    #pragma unroll
    for (int r = 0; r < 4; ++r) {
      float mk0 = Mb[(size_t)r * 1024 + s0];
      float mk1 = Mb[(size_t)r * 1024 + s0 + 16];
      float a0 = fmaf(sc0[r], QSCALE_LOG2E, mk0 * LOG2E);
      float a1 = fmaf(sc1[r], QSCALE_LOG2E, mk1 * LOG2E);
      p0[r] = a0; p1[r] = a1;
      tmax[r] = fmaxf(a0, a1);
    }
    // row-max across the 16 lanes that share a row-group
    #pragma unroll
    for (int r = 0; r < 4; ++r) {
      float tv = tmax[r];
      tv = fmaxf(tv, __shfl_xor(tv, 1));
      tv = fmaxf(tv, __shfl_xor(tv, 2));
      tv = fmaxf(tv, __shfl_xor(tv, 4));
      tv = fmaxf(tv, __shfl_xor(tv, 8));
      tmax[r] = tv;
    }
    float corr[4];
    #pragma unroll
    for (int r = 0; r < 4; ++r) {
      float mn = fmaxf(m2[r], tmax[r]);
      corr[r] = exp2f(m2[r] - mn);
      m2[r] = mn;
      float e0 = exp2f(p0[r] - mn);
      float e1 = exp2f(p1[r] - mn);
      p0[r] = e0; p1[r] = e1;
      float ss = e0 + e1;
      ss += __shfl_xor(ss, 1);
      ss += __shfl_xor(ss, 2);
      ss += __shfl_xor(ss, 4);
      ss += __shfl_xor(ss, 8);
      lsum[r] = lsum[r] * corr[r] + ss;
    }
    #pragma unroll
    for (int dt = 0; dt < 4; ++dt) {
      #pragma unroll
      for (int r = 0; r < 4; ++r) oacc[dt][r] *= corr[r];
    }

    // P (D-layout) -> LDS row-major [16 q][32 s] bf16
    #pragma unroll
    for (int r = 0; r < 4; ++r) {
      int rowb = (lgrp * 4 + r) * 64;
      *reinterpret_cast<bf16*>(Pb + rowb + lrow * 2)      = (bf16)p0[r];
      *reinterpret_cast<bf16*>(Pb + rowb + 32 + lrow * 2) = (bf16)p1[r];
    }
    // per-wave buffer: DS ops execute in order within a wave; just stop the
    // compiler from reordering across the write->read boundary.
    __builtin_amdgcn_wave_barrier();
    asm volatile("" ::: "memory");
    bf16x8 pf = *reinterpret_cast<const bf16x8*>(Pb + lrow * 64 + lgrp * 16);
    asm volatile("" ::: "memory");

    // PV: O[16q x 64d] += P[16x32] * V[32 x 64]
    #pragma unroll
    for (int dt = 0; dt < 4; ++dt) {
      bf16x8 vf = *reinterpret_cast<const bf16x8*>(Vb + (size_t)(dt * 16) * 1024 + s0);
      oacc[dt] = __builtin_amdgcn_mfma_f32_16x16x32_bf16(pf, vf, oacc[dt], 0, 0, 0);
    }
    __builtin_amdgcn_wave_barrier();
    asm volatile("" ::: "memory");
  }

  float inv[4];
  #pragma unroll
  for (int r = 0; r < 4; ++r) inv[r] = 1.0f / lsum[r];

  const int n = nh >> 3, h = nh & 7;
  bf16* Ob = Ows + ((size_t)(n * 1024 + q0 + lgrp * 4)) * 512 + h * 64 + lrow;
  #pragma unroll
  for (int dt = 0; dt < 4; ++dt)
    #pragma unroll
    for (int r = 0; r < 4; ++r)
      Ob[(size_t)r * 512 + dt * 16] = (bf16)(oacc[dt][r] * inv[r]);
}

// ---------------------------------------------------------------------------
// Kernel 3: output projection. grid = 64 * 4 = 256 blocks.
// out[8192x512] = O[8192x512](bf16) @ Wo[512x512]^T + bo   (fp32 out)
// ---------------------------------------------------------------------------
__global__ __launch_bounds__(256) void out_gemm(
    const bf16* __restrict__ Ows, const float* __restrict__ Wo,
    const float* __restrict__ bo, float* __restrict__ out) {
  __shared__ __align__(16) bf16 lA[128 * 64];
  __shared__ __align__(16) bf16 lB[128 * 64];
  char* lAb = (char*)lA;
  char* lBb = (char*)lB;

  const int bx = blockIdx.x;
  const int mt = bx >> 2;
  const int nt = bx & 3;
  const int tid = threadIdx.x;
  const int lane = tid & 63, wid = tid >> 6;
  const int wr = wid >> 1, wc = wid & 1;
  const int lrow = lane & 15, lgrp = lane >> 4;

  const bf16*  Abase = Ows + (size_t)(mt * 128) * 512;
  const float* Wbase = Wo  + (size_t)(nt * 128) * 512;

  const f32x4 fz = {0.f, 0.f, 0.f, 0.f};
  f32x4 acc[4][4];
  #pragma unroll
  for (int i = 0; i < 4; ++i)
    #pragma unroll
    for (int j = 0; j < 4; ++j) acc[i][j] = fz;

  for (int k0 = 0; k0 < 512; k0 += 64) {
    __syncthreads();
    stage_bf16_tile(Abase + k0, 512, lAb, tid);
    stage_f32_tile(Wbase + k0, 512, lBb, tid);
    __syncthreads();
    #pragma unroll
    for (int kk = 0; kk < 2; ++kk) {
      bf16x8 af[4], bfr[4];
      #pragma unroll
      for (int mf = 0; mf < 4; ++mf) {
        int row  = wr * 64 + mf * 16 + lrow;
        int byte = (row << 7) + ((((kk << 2) | lgrp) ^ (row & 7)) << 4);
        af[mf] = *reinterpret_cast<const bf16x8*>(lAb + byte);
      }
      #pragma unroll
      for (int nf = 0; nf < 4; ++nf) {
        int row  = wc * 64 + nf * 16 + lrow;
        int byte = (row << 7) + ((((kk << 2) | lgrp) ^ (row & 7)) << 4);
        bfr[nf] = *reinterpret_cast<const bf16x8*>(lBb + byte);
      }
      #pragma unroll
      for (int mf = 0; mf < 4; ++mf)
        #pragma unroll
        for (int nf = 0; nf < 4; ++nf)
          acc[mf][nf] = __builtin_amdgcn_mfma_f32_16x16x32_bf16(
              af[mf], bfr[nf], acc[mf][nf], 0, 0, 0);
    }
  }

  float bcol[4];
  #pragma unroll
  for (int nf = 0; nf < 4; ++nf)
    bcol[nf] = bo[nt * 128 + wc * 64 + nf * 16 + lrow];

  #pragma unroll
  for (int mf = 0; mf < 4; ++mf) {
    #pragma unroll
    for (int nf = 0; nf < 4; ++nf) {
      #pragma unroll
      for (int r = 0; r < 4; ++r) {
        int grow = mt * 128 + wr * 64 + mf * 16 + lgrp * 4 + r;
        int col  = nt * 128 + wc * 64 + nf * 16 + lrow;
        out[(size_t)grow * 512 + col] = acc[mf][nf][r] + bcol[nf];
      }
    }
  }
}

// ---------------------------------------------------------------------------
extern "C" void kernel_launch(void* const* d_in, const int* in_sizes, int n_in,
                              void* d_out, int out_size, void* d_ws, size_t ws_size,
                              hipStream_t stream) {
  const float* qc   = (const float*)d_in[0];
  const float* qp   = (const float*)d_in[1];
  const float* kc   = (const float*)d_in[2];
  const float* kp   = (const float*)d_in[3];
  const float* vin  = (const float*)d_in[4];
  const float* mask = (const float*)d_in[5];
  const float* Wqc  = (const float*)d_in[6];
  const float* bqc  = (const float*)d_in[7];
  const float* Wqp  = (const float*)d_in[8];
  const float* bqp  = (const float*)d_in[9];
  const float* Wkc  = (const float*)d_in[10];
  const float* bkc  = (const float*)d_in[11];
  const float* Wkp  = (const float*)d_in[12];
  const float* bkp  = (const float*)d_in[13];
  const float* Wv   = (const float*)d_in[14];
  const float* bv   = (const float*)d_in[15];
  const float* Wo   = (const float*)d_in[16];
  const float* bo   = (const float*)d_in[17];

  bf16* Qws  = (bf16*)d_ws;                  // (8,8,1024,128)  16 MB
  bf16* Kws  = Qws  + (size_t)8 * 1024 * 1024;  // (8,8,1024,128)  16 MB
  bf16* Vtws = Kws  + (size_t)8 * 1024 * 1024;  // (8,8,64,1024)    8 MB
  bf16* Ows  = Vtws + (size_t)4 * 1024 * 1024;  // (8192,512)       8 MB

  proj_gemm<<<dim3(1280), dim3(256), 0, stream>>>(
      qc, qp, kc, kp, vin, Wqc, bqc, Wqp, bqp, Wkc, bkc, Wkp, bkp, Wv, bv,
      Qws, Kws, Vtws);
  attn_fwd<<<dim3(1024), dim3(256), 0, stream>>>(Qws, Kws, Vtws, mask, Ows);
  out_gemm<<<dim3(256), dim3(256), 0, stream>>>(Ows, Wo, bo, (float*)d_out);
}

// Round 2
// 296.271 us; speedup vs baseline: 1.0352x; 1.0352x over previous
//
#include <hip/hip_runtime.h>
#include <hip/hip_bf16.h>

typedef __bf16 bf16;
typedef __bf16 bf16x8 __attribute__((ext_vector_type(8)));
typedef float  f32x4  __attribute__((ext_vector_type(4)));

#define LOG2E        1.4426950408889634f
#define QSCALE_LOG2E 0.18033688011112043f   /* log2(e)/8 */

// ---------------------------------------------------------------------------
// LDS staging helpers: [128 rows][64 k] bf16 tile, 128B rows, 16B chunks
// XOR-swizzled: chunk' = chunk ^ (row & 7). Write/read use the same involution.
// ---------------------------------------------------------------------------
__device__ __forceinline__ void stage_f32_tile(const float* __restrict__ src, int ld,
                                               char* dst, int tid) {
  #pragma unroll
  for (int t = 0; t < 8; ++t) {
    int c8  = tid + t * 256;          // 2048 8-byte units = 128 rows * 16
    int row = c8 >> 4;
    int h8  = c8 & 15;
    const f32x4 v = *reinterpret_cast<const f32x4*>(src + row * ld + h8 * 4);
    union { bf16 h[4]; unsigned long long u; } pk;
    pk.h[0] = (bf16)v[0]; pk.h[1] = (bf16)v[1];
    pk.h[2] = (bf16)v[2]; pk.h[3] = (bf16)v[3];
    int byte = (row << 7) + ((((h8 >> 1) ^ (row & 7)) << 4) | ((h8 & 1) << 3));
    *reinterpret_cast<unsigned long long*>(dst + byte) = pk.u;
  }
}

__device__ __forceinline__ void stage_bf16_tile(const bf16* __restrict__ src, int ld,
                                                char* dst, int tid) {
  #pragma unroll
  for (int t = 0; t < 4; ++t) {
    int c   = tid + t * 256;          // 1024 16-byte chunks = 128 rows * 8
    int row = c >> 3;
    int ck  = c & 7;
    const bf16x8 v = *reinterpret_cast<const bf16x8*>(src + row * ld + ck * 8);
    int byte = (row << 7) + (((ck ^ (row & 7)) << 4));
    *reinterpret_cast<bf16x8*>(dst + byte) = v;
  }
}

// ---------------------------------------------------------------------------
// Kernel 1: all 5 projection GEMMs. grid = 5 * 64 * 4 = 1280 blocks, 256 thr.
// ---------------------------------------------------------------------------
__global__ __launch_bounds__(256) void proj_gemm(
    const float* __restrict__ qc, const float* __restrict__ qp,
    const float* __restrict__ kc, const float* __restrict__ kp,
    const float* __restrict__ vin,
    const float* __restrict__ Wqc, const float* __restrict__ bqc,
    const float* __restrict__ Wqp, const float* __restrict__ bqp,
    const float* __restrict__ Wkc, const float* __restrict__ bkc,
    const float* __restrict__ Wkp, const float* __restrict__ bkp,
    const float* __restrict__ Wv,  const float* __restrict__ bv,
    bf16* __restrict__ Qws, bf16* __restrict__ Kws, bf16* __restrict__ Vtws) {
  __shared__ __align__(16) bf16 lA[128 * 64];
  __shared__ __align__(16) bf16 lB[128 * 64];
  char* lAb = (char*)lA;
  char* lBb = (char*)lB;

  const int bx = blockIdx.x;
  const int g  = bx >> 8;             // which of the 5 GEMMs
  const int mt = (bx & 255) >> 2;     // 64 M-tiles
  const int nt = bx & 3;              // 4 N-tiles

  const float *A, *W, *bias;
  if      (g == 0) { A = qc;  W = Wqc; bias = bqc; }
  else if (g == 1) { A = qp;  W = Wqp; bias = bqp; }
  else if (g == 2) { A = kc;  W = Wkc; bias = bkc; }
  else if (g == 3) { A = kp;  W = Wkp; bias = bkp; }
  else             { A = vin; W = Wv;  bias = bv;  }

  const int tid  = threadIdx.x;
  const int lane = tid & 63, wid = tid >> 6;
  const int wr = wid >> 1, wc = wid & 1;
  const int lrow = lane & 15, lgrp = lane >> 4;

  const float* Abase = A + (size_t)(mt * 128) * 512;
  const float* Wbase = W + (size_t)(nt * 128) * 512;

  const f32x4 fz = {0.f, 0.f, 0.f, 0.f};
  f32x4 acc[4][4];
  #pragma unroll
  for (int i = 0; i < 4; ++i)
    #pragma unroll
    for (int j = 0; j < 4; ++j) acc[i][j] = fz;

  for (int k0 = 0; k0 < 512; k0 += 64) {
    __syncthreads();
    stage_f32_tile(Abase + k0, 512, lAb, tid);
    stage_f32_tile(Wbase + k0, 512, lBb, tid);
    __syncthreads();
    #pragma unroll
    for (int kk = 0; kk < 2; ++kk) {
      bf16x8 af[4], bfr[4];
      #pragma unroll
      for (int mf = 0; mf < 4; ++mf) {
        int row  = wr * 64 + mf * 16 + lrow;
        int byte = (row << 7) + ((((kk << 2) | lgrp) ^ (row & 7)) << 4);
        af[mf] = *reinterpret_cast<const bf16x8*>(lAb + byte);
      }
      #pragma unroll
      for (int nf = 0; nf < 4; ++nf) {
        int row  = wc * 64 + nf * 16 + lrow;
        int byte = (row << 7) + ((((kk << 2) | lgrp) ^ (row & 7)) << 4);
        bfr[nf] = *reinterpret_cast<const bf16x8*>(lBb + byte);
      }
      #pragma unroll
      for (int mf = 0; mf < 4; ++mf)
        #pragma unroll
        for (int nf = 0; nf < 4; ++nf)
          acc[mf][nf] = __builtin_amdgcn_mfma_f32_16x16x32_bf16(
              af[mf], bfr[nf], acc[mf][nf], 0, 0, 0);
    }
  }

  float bcol[4];
  #pragma unroll
  for (int nf = 0; nf < 4; ++nf)
    bcol[nf] = bias[nt * 128 + wc * 64 + nf * 16 + lrow];

  #pragma unroll
  for (int mf = 0; mf < 4; ++mf) {
    #pragma unroll
    for (int nf = 0; nf < 4; ++nf) {
      #pragma unroll
      for (int r = 0; r < 4; ++r) {
        int grow = mt * 128 + wr * 64 + mf * 16 + lgrp * 4 + r;  // 0..8191
        int col  = nt * 128 + wc * 64 + nf * 16 + lrow;          // 0..511
        float vv = acc[mf][nf][r] + bcol[nf];
        bf16 hb  = (bf16)vv;
        int n = grow >> 10, tt = grow & 1023;
        if (g < 2) {
          int j = (g << 9) + col;     // 0..1023
          Qws[(size_t)((((n << 3) + (j >> 7)) << 10) | tt) * 128 + (j & 127)] = hb;
        } else if (g < 4) {
          int j = ((g - 2) << 9) + col;
          Kws[(size_t)((((n << 3) + (j >> 7)) << 10) | tt) * 128 + (j & 127)] = hb;
        } else {
          int h = col >> 6, d = col & 63;
          Vtws[(size_t)((((n << 3) + h) << 6) + d) * 1024 + tt] = hb;
        }
      }
    }
  }
}

// ---------------------------------------------------------------------------
// Kernel 2: flash attention, software-pipelined.
// grid = 64 (n,h) * 16 q-tiles = 1024 blocks; 4 waves x 16 queries.
// K/V/mask direct from global (L2/L3-resident); next-step K + mask prefetched
// into registers; online softmax base-2 with per-lane deferred denominator.
// ---------------------------------------------------------------------------
__global__ __launch_bounds__(256) void attn_fwd(
    const bf16* __restrict__ Qws, const bf16* __restrict__ Kws,
    const bf16* __restrict__ Vtws, const float* __restrict__ mask,
    bf16* __restrict__ Ows) {
  __shared__ __align__(16) bf16 Pl[4][16][32];

  const int bx = blockIdx.x;
  const int nh = bx >> 4;
  const int qt = bx & 15;
  const int tid = threadIdx.x;
  const int lane = tid & 63, wid = tid >> 6;
  const int lrow = lane & 15, lgrp = lane >> 4;
  const int q0 = qt * 64 + wid * 16;

  // Q fragments (held for the whole loop)
  const bf16* Qb = Qws + ((size_t)(nh * 1024 + q0 + lrow)) * 128 + lgrp * 8;
  bf16x8 qf[4];
  #pragma unroll
  for (int kk = 0; kk < 4; ++kk)
    qf[kk] = *reinterpret_cast<const bf16x8*>(Qb + kk * 32);

  const bf16*  Kb = Kws  + ((size_t)(nh * 1024 + lrow)) * 128 + lgrp * 8;
  const bf16*  Vb = Vtws + ((size_t)(nh * 64 + lrow)) * 1024 + lgrp * 8;
  const float* Mb = mask + ((size_t)(nh * 1024 + q0 + lgrp * 4)) * 1024 + lrow;

  char* Pb = (char*)&Pl[wid][0][0];

  const f32x4 fz = {0.f, 0.f, 0.f, 0.f};
  f32x4 oacc[4];
  #pragma unroll
  for (int dt = 0; dt < 4; ++dt) oacc[dt] = fz;
  float m2[4], lsum[4];
  #pragma unroll
  for (int r = 0; r < 4; ++r) { m2[r] = -1e30f; lsum[r] = 0.f; }

  // one 32-key step: compute with (KF, MK) at s0, prefetch (KN, MN) at sp
  auto step = [&](int s0, bf16x8 (&KF)[8], float (&MK)[8],
                  bf16x8 (&KN)[8], float (&MN)[8], int sp) {
    // ---- issue next-step prefetch first (independent of this step) ----
    #pragma unroll
    for (int kk = 0; kk < 4; ++kk) {
      KN[kk]     = *reinterpret_cast<const bf16x8*>(Kb + (size_t)sp * 128 + kk * 32);
      KN[4 + kk] = *reinterpret_cast<const bf16x8*>(Kb + (size_t)(sp + 16) * 128 + kk * 32);
    }
    #pragma unroll
    for (int r = 0; r < 4; ++r) {
      MN[r]     = Mb[(size_t)r * 1024 + sp];
      MN[4 + r] = Mb[(size_t)r * 1024 + sp + 16];
    }
    // ---- V for this step (issue early, consume late) ----
    bf16x8 vf[4];
    #pragma unroll
    for (int dt = 0; dt < 4; ++dt)
      vf[dt] = *reinterpret_cast<const bf16x8*>(Vb + (size_t)(dt * 16) * 1024 + s0);

    // ---- QK^T: two 16-key column tiles ----
    f32x4 sc0 = fz, sc1 = fz;
    #pragma unroll
    for (int kk = 0; kk < 4; ++kk)
      sc0 = __builtin_amdgcn_mfma_f32_16x16x32_bf16(qf[kk], KF[kk], sc0, 0, 0, 0);
    #pragma unroll
    for (int kk = 0; kk < 4; ++kk)
      sc1 = __builtin_amdgcn_mfma_f32_16x16x32_bf16(qf[kk], KF[4 + kk], sc1, 0, 0, 0);

    // logits (base-2): a = s * log2e/8 + mask * log2e
    float p0[4], p1[4], tmax[4];
    #pragma unroll
    for (int r = 0; r < 4; ++r) {
      float a0 = fmaf(sc0[r], QSCALE_LOG2E, MK[r] * LOG2E);
      float a1 = fmaf(sc1[r], QSCALE_LOG2E, MK[4 + r] * LOG2E);
      p0[r] = a0; p1[r] = a1;
      tmax[r] = fmaxf(a0, a1);
    }
    // row-max across the 16 lanes sharing a row-group
    #pragma unroll
    for (int r = 0; r < 4; ++r) {
      float tv = tmax[r];
      tv = fmaxf(tv, __shfl_xor(tv, 1));
      tv = fmaxf(tv, __shfl_xor(tv, 2));
      tv = fmaxf(tv, __shfl_xor(tv, 4));
      tv = fmaxf(tv, __shfl_xor(tv, 8));
      tmax[r] = tv;
    }
    float corr[4];
    #pragma unroll
    for (int r = 0; r < 4; ++r) {
      float mn = fmaxf(m2[r], tmax[r]);
      corr[r] = exp2f(m2[r] - mn);
      m2[r] = mn;
      float e0 = exp2f(p0[r] - mn);
      float e1 = exp2f(p1[r] - mn);
      p0[r] = e0; p1[r] = e1;
      // denominator: per-lane partial (corr is row-uniform); reduce at the end
      lsum[r] = lsum[r] * corr[r] + (e0 + e1);
    }
    #pragma unroll
    for (int dt = 0; dt < 4; ++dt) {
      #pragma unroll
      for (int r = 0; r < 4; ++r) oacc[dt][r] *= corr[r];
    }

    // P (D-layout) -> LDS row-major [16 q][32 s] bf16  (per-wave buffer)
    #pragma unroll
    for (int r = 0; r < 4; ++r) {
      int rowb = (lgrp * 4 + r) * 64;
      *reinterpret_cast<bf16*>(Pb + rowb + lrow * 2)      = (bf16)p0[r];
      *reinterpret_cast<bf16*>(Pb + rowb + 32 + lrow * 2) = (bf16)p1[r];
    }
    __builtin_amdgcn_wave_barrier();
    __builtin_amdgcn_sched_barrier(0);
    bf16x8 pf = *reinterpret_cast<const bf16x8*>(Pb + lrow * 64 + lgrp * 16);
    __builtin_amdgcn_wave_barrier();
    __builtin_amdgcn_sched_barrier(0);

    // PV: O[16q x 64d] += P[16x32] * V[32 x 64]
    #pragma unroll
    for (int dt = 0; dt < 4; ++dt)
      oacc[dt] = __builtin_amdgcn_mfma_f32_16x16x32_bf16(pf, vf[dt], oacc[dt], 0, 0, 0);
  };

  bf16x8 kA[8], kB[8];
  float  mA[8], mB[8];
  // prologue: load tile s=0 into A buffers
  #pragma unroll
  for (int kk = 0; kk < 4; ++kk) {
    kA[kk]     = *reinterpret_cast<const bf16x8*>(Kb + (size_t)0 * 128 + kk * 32);
    kA[4 + kk] = *reinterpret_cast<const bf16x8*>(Kb + (size_t)16 * 128 + kk * 32);
  }
  #pragma unroll
  for (int r = 0; r < 4; ++r) {
    mA[r]     = Mb[(size_t)r * 1024];
    mA[4 + r] = Mb[(size_t)r * 1024 + 16];
  }

  for (int tt = 0; tt < 16; ++tt) {
    int s0 = tt * 64;
    step(s0,      kA, mA, kB, mB, s0 + 32);
    step(s0 + 32, kB, mB, kA, mA, (tt == 15) ? 0 : (s0 + 64));
  }

  // final denominator reduce (deferred from the loop)
  #pragma unroll
  for (int r = 0; r < 4; ++r) {
    float ss = lsum[r];
    ss += __shfl_xor(ss, 1);
    ss += __shfl_xor(ss, 2);
    ss += __shfl_xor(ss, 4);
    ss += __shfl_xor(ss, 8);
    lsum[r] = 1.0f / ss;
  }

  const int n = nh >> 3, h = nh & 7;
  bf16* Ob = Ows + ((size_t)(n * 1024 + q0 + lgrp * 4)) * 512 + h * 64 + lrow;
  #pragma unroll
  for (int dt = 0; dt < 4; ++dt)
    #pragma unroll
    for (int r = 0; r < 4; ++r)
      Ob[(size_t)r * 512 + dt * 16] = (bf16)(oacc[dt][r] * lsum[r]);
}

// ---------------------------------------------------------------------------
// Kernel 3: output projection. grid = 64 * 4 = 256 blocks.
// ---------------------------------------------------------------------------
__global__ __launch_bounds__(256) void out_gemm(
    const bf16* __restrict__ Ows, const float* __restrict__ Wo,
    const float* __restrict__ bo, float* __restrict__ out) {
  __shared__ __align__(16) bf16 lA[128 * 64];
  __shared__ __align__(16) bf16 lB[128 * 64];
  char* lAb = (char*)lA;
  char* lBb = (char*)lB;

  const int bx = blockIdx.x;
  const int mt = bx >> 2;
  const int nt = bx & 3;
  const int tid = threadIdx.x;
  const int lane = tid & 63, wid = tid >> 6;
  const int wr = wid >> 1, wc = wid & 1;
  const int lrow = lane & 15, lgrp = lane >> 4;

  const bf16*  Abase = Ows + (size_t)(mt * 128) * 512;
  const float* Wbase = Wo  + (size_t)(nt * 128) * 512;

  const f32x4 fz = {0.f, 0.f, 0.f, 0.f};
  f32x4 acc[4][4];
  #pragma unroll
  for (int i = 0; i < 4; ++i)
    #pragma unroll
    for (int j = 0; j < 4; ++j) acc[i][j] = fz;

  for (int k0 = 0; k0 < 512; k0 += 64) {
    __syncthreads();
    stage_bf16_tile(Abase + k0, 512, lAb, tid);
    stage_f32_tile(Wbase + k0, 512, lBb, tid);
    __syncthreads();
    #pragma unroll
    for (int kk = 0; kk < 2; ++kk) {
      bf16x8 af[4], bfr[4];
      #pragma unroll
      for (int mf = 0; mf < 4; ++mf) {
        int row  = wr * 64 + mf * 16 + lrow;
        int byte = (row << 7) + ((((kk << 2) | lgrp) ^ (row & 7)) << 4);
        af[mf] = *reinterpret_cast<const bf16x8*>(lAb + byte);
      }
      #pragma unroll
      for (int nf = 0; nf < 4; ++nf) {
        int row  = wc * 64 + nf * 16 + lrow;
        int byte = (row << 7) + ((((kk << 2) | lgrp) ^ (row & 7)) << 4);
        bfr[nf] = *reinterpret_cast<const bf16x8*>(lBb + byte);
      }
      #pragma unroll
      for (int mf = 0; mf < 4; ++mf)
        #pragma unroll
        for (int nf = 0; nf < 4; ++nf)
          acc[mf][nf] = __builtin_amdgcn_mfma_f32_16x16x32_bf16(
              af[mf], bfr[nf], acc[mf][nf], 0, 0, 0);
    }
  }

  float bcol[4];
  #pragma unroll
  for (int nf = 0; nf < 4; ++nf)
    bcol[nf] = bo[nt * 128 + wc * 64 + nf * 16 + lrow];

  #pragma unroll
  for (int mf = 0; mf < 4; ++mf) {
    #pragma unroll
    for (int nf = 0; nf < 4; ++nf) {
      #pragma unroll
      for (int r = 0; r < 4; ++r) {
        int grow = mt * 128 + wr * 64 + mf * 16 + lgrp * 4 + r;
        int col  = nt * 128 + wc * 64 + nf * 16 + lrow;
        out[(size_t)grow * 512 + col] = acc[mf][nf][r] + bcol[nf];
      }
    }
  }
}

// ---------------------------------------------------------------------------
extern "C" void kernel_launch(void* const* d_in, const int* in_sizes, int n_in,
                              void* d_out, int out_size, void* d_ws, size_t ws_size,
                              hipStream_t stream) {
  const float* qc   = (const float*)d_in[0];
  const float* qp   = (const float*)d_in[1];
  const float* kc   = (const float*)d_in[2];
  const float* kp   = (const float*)d_in[3];
  const float* vin  = (const float*)d_in[4];
  const float* mask = (const float*)d_in[5];
  const float* Wqc  = (const float*)d_in[6];
  const float* bqc  = (const float*)d_in[7];
  const float* Wqp  = (const float*)d_in[8];
  const float* bqp  = (const float*)d_in[9];
  const float* Wkc  = (const float*)d_in[10];
  const float* bkc  = (const float*)d_in[11];
  const float* Wkp  = (const float*)d_in[12];
  const float* bkp  = (const float*)d_in[13];
  const float* Wv   = (const float*)d_in[14];
  const float* bv   = (const float*)d_in[15];
  const float* Wo   = (const float*)d_in[16];
  const float* bo   = (const float*)d_in[17];

  bf16* Qws  = (bf16*)d_ws;                     // (8,8,1024,128)  16 MB
  bf16* Kws  = Qws  + (size_t)8 * 1024 * 1024;  // (8,8,1024,128)  16 MB
  bf16* Vtws = Kws  + (size_t)8 * 1024 * 1024;  // (8,8,64,1024)    8 MB
  bf16* Ows  = Vtws + (size_t)4 * 1024 * 1024;  // (8192,512)       8 MB

  proj_gemm<<<dim3(1280), dim3(256), 0, stream>>>(
      qc, qp, kc, kp, vin, Wqc, bqc, Wqp, bqp, Wkc, bkc, Wkp, bkp, Wv, bv,
      Qws, Kws, Vtws);
  attn_fwd<<<dim3(1024), dim3(256), 0, stream>>>(Qws, Kws, Vtws, mask, Ows);
  out_gemm<<<dim3(256), dim3(256), 0, stream>>>(Ows, Wo, bo, (float*)d_out);
}

// Round 3
// 291.408 us; speedup vs baseline: 1.0525x; 1.0167x over previous
//
#include <hip/hip_runtime.h>
#include <hip/hip_bf16.h>

typedef __bf16 bf16;
typedef __bf16 bf16x8 __attribute__((ext_vector_type(8)));
typedef float  f32x4  __attribute__((ext_vector_type(4)));

#define LOG2E        1.4426950408889634f
#define QSCALE_LOG2E 0.18033688011112043f   /* log2(e)/8 */
#define DEFER_THR    20.0f                  /* rescale only if logit2 > m+20 */

// ---------------------------------------------------------------------------
// LDS staging helpers: [128 rows][64 k] bf16 tile, 128B rows, 16B chunks
// XOR-swizzled: chunk' = chunk ^ (row & 7). Write/read use the same involution.
// ---------------------------------------------------------------------------
__device__ __forceinline__ void stage_f32_tile(const float* __restrict__ src, int ld,
                                               char* dst, int tid) {
  #pragma unroll
  for (int t = 0; t < 8; ++t) {
    int c8  = tid + t * 256;          // 2048 8-byte units = 128 rows * 16
    int row = c8 >> 4;
    int h8  = c8 & 15;
    const f32x4 v = *reinterpret_cast<const f32x4*>(src + row * ld + h8 * 4);
    union { bf16 h[4]; unsigned long long u; } pk;
    pk.h[0] = (bf16)v[0]; pk.h[1] = (bf16)v[1];
    pk.h[2] = (bf16)v[2]; pk.h[3] = (bf16)v[3];
    int byte = (row << 7) + ((((h8 >> 1) ^ (row & 7)) << 4) | ((h8 & 1) << 3));
    *reinterpret_cast<unsigned long long*>(dst + byte) = pk.u;
  }
}

__device__ __forceinline__ void stage_bf16_tile(const bf16* __restrict__ src, int ld,
                                                char* dst, int tid) {
  #pragma unroll
  for (int t = 0; t < 4; ++t) {
    int c   = tid + t * 256;          // 1024 16-byte chunks = 128 rows * 8
    int row = c >> 3;
    int ck  = c & 7;
    const bf16x8 v = *reinterpret_cast<const bf16x8*>(src + row * ld + ck * 8);
    int byte = (row << 7) + (((ck ^ (row & 7)) << 4));
    *reinterpret_cast<bf16x8*>(dst + byte) = v;
  }
}

// ---------------------------------------------------------------------------
// Kernel 1: all 5 projection GEMMs. grid = 5 * 64 * 4 = 1280 blocks, 256 thr.
// ---------------------------------------------------------------------------
__global__ __launch_bounds__(256) void proj_gemm(
    const float* __restrict__ qc, const float* __restrict__ qp,
    const float* __restrict__ kc, const float* __restrict__ kp,
    const float* __restrict__ vin,
    const float* __restrict__ Wqc, const float* __restrict__ bqc,
    const float* __restrict__ Wqp, const float* __restrict__ bqp,
    const float* __restrict__ Wkc, const float* __restrict__ bkc,
    const float* __restrict__ Wkp, const float* __restrict__ bkp,
    const float* __restrict__ Wv,  const float* __restrict__ bv,
    bf16* __restrict__ Qws, bf16* __restrict__ Kws, bf16* __restrict__ Vtws) {
  __shared__ __align__(16) bf16 lA[128 * 64];
  __shared__ __align__(16) bf16 lB[128 * 64];
  char* lAb = (char*)lA;
  char* lBb = (char*)lB;

  const int bx = blockIdx.x;
  const int g  = bx >> 8;             // which of the 5 GEMMs
  const int mt = (bx & 255) >> 2;     // 64 M-tiles
  const int nt = bx & 3;              // 4 N-tiles

  const float *A, *W, *bias;
  if      (g == 0) { A = qc;  W = Wqc; bias = bqc; }
  else if (g == 1) { A = qp;  W = Wqp; bias = bqp; }
  else if (g == 2) { A = kc;  W = Wkc; bias = bkc; }
  else if (g == 3) { A = kp;  W = Wkp; bias = bkp; }
  else             { A = vin; W = Wv;  bias = bv;  }

  const int tid  = threadIdx.x;
  const int lane = tid & 63, wid = tid >> 6;
  const int wr = wid >> 1, wc = wid & 1;
  const int lrow = lane & 15, lgrp = lane >> 4;

  const float* Abase = A + (size_t)(mt * 128) * 512;
  const float* Wbase = W + (size_t)(nt * 128) * 512;

  const f32x4 fz = {0.f, 0.f, 0.f, 0.f};
  f32x4 acc[4][4];
  #pragma unroll
  for (int i = 0; i < 4; ++i)
    #pragma unroll
    for (int j = 0; j < 4; ++j) acc[i][j] = fz;

  for (int k0 = 0; k0 < 512; k0 += 64) {
    __syncthreads();
    stage_f32_tile(Abase + k0, 512, lAb, tid);
    stage_f32_tile(Wbase + k0, 512, lBb, tid);
    __syncthreads();
    #pragma unroll
    for (int kk = 0; kk < 2; ++kk) {
      bf16x8 af[4], bfr[4];
      #pragma unroll
      for (int mf = 0; mf < 4; ++mf) {
        int row  = wr * 64 + mf * 16 + lrow;
        int byte = (row << 7) + ((((kk << 2) | lgrp) ^ (row & 7)) << 4);
        af[mf] = *reinterpret_cast<const bf16x8*>(lAb + byte);
      }
      #pragma unroll
      for (int nf = 0; nf < 4; ++nf) {
        int row  = wc * 64 + nf * 16 + lrow;
        int byte = (row << 7) + ((((kk << 2) | lgrp) ^ (row & 7)) << 4);
        bfr[nf] = *reinterpret_cast<const bf16x8*>(lBb + byte);
      }
      #pragma unroll
      for (int mf = 0; mf < 4; ++mf)
        #pragma unroll
        for (int nf = 0; nf < 4; ++nf)
          acc[mf][nf] = __builtin_amdgcn_mfma_f32_16x16x32_bf16(
              af[mf], bfr[nf], acc[mf][nf], 0, 0, 0);
    }
  }

  float bcol[4];
  #pragma unroll
  for (int nf = 0; nf < 4; ++nf)
    bcol[nf] = bias[nt * 128 + wc * 64 + nf * 16 + lrow];

  #pragma unroll
  for (int mf = 0; mf < 4; ++mf) {
    #pragma unroll
    for (int nf = 0; nf < 4; ++nf) {
      #pragma unroll
      for (int r = 0; r < 4; ++r) {
        int grow = mt * 128 + wr * 64 + mf * 16 + lgrp * 4 + r;  // 0..8191
        int col  = nt * 128 + wc * 64 + nf * 16 + lrow;          // 0..511
        float vv = acc[mf][nf][r] + bcol[nf];
        bf16 hb  = (bf16)vv;
        int n = grow >> 10, tt = grow & 1023;
        if (g < 2) {
          int j = (g << 9) + col;     // 0..1023
          Qws[(size_t)((((n << 3) + (j >> 7)) << 10) | tt) * 128 + (j & 127)] = hb;
        } else if (g < 4) {
          int j = ((g - 2) << 9) + col;
          Kws[(size_t)((((n << 3) + (j >> 7)) << 10) | tt) * 128 + (j & 127)] = hb;
        } else {
          int h = col >> 6, d = col & 63;
          Vtws[(size_t)((((n << 3) + h) << 6) + d) * 1024 + tt] = hb;
        }
      }
    }
  }
}

// ---------------------------------------------------------------------------
// Kernel 2: flash attention, defer-max (no per-step cross-lane reduction).
// grid = 64 (n,h) * 16 q-tiles = 1024 blocks; 4 waves x 16 queries.
// Running max fixed at 0 unless a logit exceeds m+20 (wave-uniform check);
// P tile double-buffered in LDS -> single sched fence per step.
// ---------------------------------------------------------------------------
__global__ __launch_bounds__(256) void attn_fwd(
    const bf16* __restrict__ Qws, const bf16* __restrict__ Kws,
    const bf16* __restrict__ Vtws, const float* __restrict__ mask,
    bf16* __restrict__ Ows) {
  __shared__ __align__(16) bf16 Pl[4][2][16][32];

  const int bx = blockIdx.x;
  const int nh = bx >> 4;
  const int qt = bx & 15;
  const int tid = threadIdx.x;
  const int lane = tid & 63, wid = tid >> 6;
  const int lrow = lane & 15, lgrp = lane >> 4;
  const int q0 = qt * 64 + wid * 16;

  // Q fragments (held for the whole loop)
  const bf16* Qb = Qws + ((size_t)(nh * 1024 + q0 + lrow)) * 128 + lgrp * 8;
  bf16x8 qf[4];
  #pragma unroll
  for (int kk = 0; kk < 4; ++kk)
    qf[kk] = *reinterpret_cast<const bf16x8*>(Qb + kk * 32);

  const bf16*  Kb = Kws  + ((size_t)(nh * 1024 + lrow)) * 128 + lgrp * 8;
  const bf16*  Vb = Vtws + ((size_t)(nh * 64 + lrow)) * 1024 + lgrp * 8;
  const float* Mb = mask + ((size_t)(nh * 1024 + q0 + lgrp * 4)) * 1024 + lrow;

  char* Pb0 = (char*)&Pl[wid][0][0][0];   // two 1KB buffers, 1KB apart

  const f32x4 fz = {0.f, 0.f, 0.f, 0.f};
  f32x4 oacc[4];
  #pragma unroll
  for (int dt = 0; dt < 4; ++dt) oacc[dt] = fz;
  float m2[4], lsum[4];
  #pragma unroll
  for (int r = 0; r < 4; ++r) { m2[r] = 0.f; lsum[r] = 0.f; }

  // one 32-key step: compute with (KF, MK) at s0, prefetch (KN, MN) at sp
  auto step = [&](int s0, int buf, bf16x8 (&KF)[8], float (&MK)[8],
                  bf16x8 (&KN)[8], float (&MN)[8], int sp) {
    // ---- issue next-step prefetch first (independent of this step) ----
    #pragma unroll
    for (int kk = 0; kk < 4; ++kk) {
      KN[kk]     = *reinterpret_cast<const bf16x8*>(Kb + (size_t)sp * 128 + kk * 32);
      KN[4 + kk] = *reinterpret_cast<const bf16x8*>(Kb + (size_t)(sp + 16) * 128 + kk * 32);
    }
    #pragma unroll
    for (int r = 0; r < 4; ++r) {
      MN[r]     = Mb[(size_t)r * 1024 + sp];
      MN[4 + r] = Mb[(size_t)r * 1024 + sp + 16];
    }
    // ---- V for this step (issue early, consume late) ----
    bf16x8 vf[4];
    #pragma unroll
    for (int dt = 0; dt < 4; ++dt)
      vf[dt] = *reinterpret_cast<const bf16x8*>(Vb + (size_t)(dt * 16) * 1024 + s0);

    // ---- QK^T: two 16-key column tiles ----
    f32x4 sc0 = fz, sc1 = fz;
    #pragma unroll
    for (int kk = 0; kk < 4; ++kk)
      sc0 = __builtin_amdgcn_mfma_f32_16x16x32_bf16(qf[kk], KF[kk], sc0, 0, 0, 0);
    #pragma unroll
    for (int kk = 0; kk < 4; ++kk)
      sc1 = __builtin_amdgcn_mfma_f32_16x16x32_bf16(qf[kk], KF[4 + kk], sc1, 0, 0, 0);

    // logits (base-2): a = s * log2e/8 + mask * log2e
    float a0r[4], a1r[4];
    bool ok = true;
    #pragma unroll
    for (int r = 0; r < 4; ++r) {
      a0r[r] = fmaf(sc0[r], QSCALE_LOG2E, MK[r] * LOG2E);
      a1r[r] = fmaf(sc1[r], QSCALE_LOG2E, MK[4 + r] * LOG2E);
      ok &= (fmaxf(a0r[r], a1r[r]) <= m2[r] + DEFER_THR);
    }
    // defer-max: rescale only when some logit exceeds m+THR (~never here)
    if (__builtin_expect(!__all(ok), 0)) {
      #pragma unroll
      for (int r = 0; r < 4; ++r) {
        float tv = fmaxf(a0r[r], a1r[r]);
        tv = fmaxf(tv, __shfl_xor(tv, 1));
        tv = fmaxf(tv, __shfl_xor(tv, 2));
        tv = fmaxf(tv, __shfl_xor(tv, 4));
        tv = fmaxf(tv, __shfl_xor(tv, 8));
        float mn = fmaxf(m2[r], tv);
        float corr = exp2f(m2[r] - mn);
        m2[r] = mn;
        lsum[r] *= corr;
        #pragma unroll
        for (int dt = 0; dt < 4; ++dt) oacc[dt][r] *= corr;
      }
    }
    float p0[4], p1[4];
    #pragma unroll
    for (int r = 0; r < 4; ++r) {
      float e0 = exp2f(a0r[r] - m2[r]);
      float e1 = exp2f(a1r[r] - m2[r]);
      p0[r] = e0; p1[r] = e1;
      lsum[r] += e0 + e1;          // per-lane partial; reduced once at the end
    }

    // P (D-layout) -> LDS row-major [16 q][32 s] bf16  (double-buffered)
    char* Pb = Pb0 + (buf << 10);
    #pragma unroll
    for (int r = 0; r < 4; ++r) {
      int rowb = (lgrp * 4 + r) * 64;
      *reinterpret_cast<bf16*>(Pb + rowb + lrow * 2)      = (bf16)p0[r];
      *reinterpret_cast<bf16*>(Pb + rowb + 32 + lrow * 2) = (bf16)p1[r];
    }
    __builtin_amdgcn_wave_barrier();
    __builtin_amdgcn_sched_barrier(0);
    bf16x8 pf = *reinterpret_cast<const bf16x8*>(Pb + lrow * 64 + lgrp * 16);

    // PV: O[16q x 64d] += P[16x32] * V[32 x 64]
    #pragma unroll
    for (int dt = 0; dt < 4; ++dt)
      oacc[dt] = __builtin_amdgcn_mfma_f32_16x16x32_bf16(pf, vf[dt], oacc[dt], 0, 0, 0);
  };

  bf16x8 kA[8], kB[8];
  float  mA[8], mB[8];
  // prologue: load tile s=0 into A buffers
  #pragma unroll
  for (int kk = 0; kk < 4; ++kk) {
    kA[kk]     = *reinterpret_cast<const bf16x8*>(Kb + (size_t)0 * 128 + kk * 32);
    kA[4 + kk] = *reinterpret_cast<const bf16x8*>(Kb + (size_t)16 * 128 + kk * 32);
  }
  #pragma unroll
  for (int r = 0; r < 4; ++r) {
    mA[r]     = Mb[(size_t)r * 1024];
    mA[4 + r] = Mb[(size_t)r * 1024 + 16];
  }

  for (int tt = 0; tt < 16; ++tt) {
    int s0 = tt * 64;
    step(s0,      0, kA, mA, kB, mB, s0 + 32);
    step(s0 + 32, 1, kB, mB, kA, mA, (tt == 15) ? 0 : (s0 + 64));
  }

  // final denominator reduce (deferred from the loop)
  #pragma unroll
  for (int r = 0; r < 4; ++r) {
    float ss = lsum[r];
    ss += __shfl_xor(ss, 1);
    ss += __shfl_xor(ss, 2);
    ss += __shfl_xor(ss, 4);
    ss += __shfl_xor(ss, 8);
    lsum[r] = 1.0f / ss;
  }

  const int n = nh >> 3, h = nh & 7;
  bf16* Ob = Ows + ((size_t)(n * 1024 + q0 + lgrp * 4)) * 512 + h * 64 + lrow;
  #pragma unroll
  for (int dt = 0; dt < 4; ++dt)
    #pragma unroll
    for (int r = 0; r < 4; ++r)
      Ob[(size_t)r * 512 + dt * 16] = (bf16)(oacc[dt][r] * lsum[r]);
}

// ---------------------------------------------------------------------------
// Kernel 3: output projection. grid = 64 * 4 = 256 blocks.
// ---------------------------------------------------------------------------
__global__ __launch_bounds__(256) void out_gemm(
    const bf16* __restrict__ Ows, const float* __restrict__ Wo,
    const float* __restrict__ bo, float* __restrict__ out) {
  __shared__ __align__(16) bf16 lA[128 * 64];
  __shared__ __align__(16) bf16 lB[128 * 64];
  char* lAb = (char*)lA;
  char* lBb = (char*)lB;

  const int bx = blockIdx.x;
  const int mt = bx >> 2;
  const int nt = bx & 3;
  const int tid = threadIdx.x;
  const int lane = tid & 63, wid = tid >> 6;
  const int wr = wid >> 1, wc = wid & 1;
  const int lrow = lane & 15, lgrp = lane >> 4;

  const bf16*  Abase = Ows + (size_t)(mt * 128) * 512;
  const float* Wbase = Wo  + (size_t)(nt * 128) * 512;

  const f32x4 fz = {0.f, 0.f, 0.f, 0.f};
  f32x4 acc[4][4];
  #pragma unroll
  for (int i = 0; i < 4; ++i)
    #pragma unroll
    for (int j = 0; j < 4; ++j) acc[i][j] = fz;

  for (int k0 = 0; k0 < 512; k0 += 64) {
    __syncthreads();
    stage_bf16_tile(Abase + k0, 512, lAb, tid);
    stage_f32_tile(Wbase + k0, 512, lBb, tid);
    __syncthreads();
    #pragma unroll
    for (int kk = 0; kk < 2; ++kk) {
      bf16x8 af[4], bfr[4];
      #pragma unroll
      for (int mf = 0; mf < 4; ++mf) {
        int row  = wr * 64 + mf * 16 + lrow;
        int byte = (row << 7) + ((((kk << 2) | lgrp) ^ (row & 7)) << 4);
        af[mf] = *reinterpret_cast<const bf16x8*>(lAb + byte);
      }
      #pragma unroll
      for (int nf = 0; nf < 4; ++nf) {
        int row  = wc * 64 + nf * 16 + lrow;
        int byte = (row << 7) + ((((kk << 2) | lgrp) ^ (row & 7)) << 4);
        bfr[nf] = *reinterpret_cast<const bf16x8*>(lBb + byte);
      }
      #pragma unroll
      for (int mf = 0; mf < 4; ++mf)
        #pragma unroll
        for (int nf = 0; nf < 4; ++nf)
          acc[mf][nf] = __builtin_amdgcn_mfma_f32_16x16x32_bf16(
              af[mf], bfr[nf], acc[mf][nf], 0, 0, 0);
    }
  }

  float bcol[4];
  #pragma unroll
  for (int nf = 0; nf < 4; ++nf)
    bcol[nf] = bo[nt * 128 + wc * 64 + nf * 16 + lrow];

  #pragma unroll
  for (int mf = 0; mf < 4; ++mf) {
    #pragma unroll
    for (int nf = 0; nf < 4; ++nf) {
      #pragma unroll
      for (int r = 0; r < 4; ++r) {
        int grow = mt * 128 + wr * 64 + mf * 16 + lgrp * 4 + r;
        int col  = nt * 128 + wc * 64 + nf * 16 + lrow;
        out[(size_t)grow * 512 + col] = acc[mf][nf][r] + bcol[nf];
      }
    }
  }
}

// ---------------------------------------------------------------------------
extern "C" void kernel_launch(void* const* d_in, const int* in_sizes, int n_in,
                              void* d_out, int out_size, void* d_ws, size_t ws_size,
                              hipStream_t stream) {
  const float* qc   = (const float*)d_in[0];
  const float* qp   = (const float*)d_in[1];
  const float* kc   = (const float*)d_in[2];
  const float* kp   = (const float*)d_in[3];
  const float* vin  = (const float*)d_in[4];
  const float* mask = (const float*)d_in[5];
  const float* Wqc  = (const float*)d_in[6];
  const float* bqc  = (const float*)d_in[7];
  const float* Wqp  = (const float*)d_in[8];
  const float* bqp  = (const float*)d_in[9];
  const float* Wkc  = (const float*)d_in[10];
  const float* bkc  = (const float*)d_in[11];
  const float* Wkp  = (const float*)d_in[12];
  const float* bkp  = (const float*)d_in[13];
  const float* Wv   = (const float*)d_in[14];
  const float* bv   = (const float*)d_in[15];
  const float* Wo   = (const float*)d_in[16];
  const float* bo   = (const float*)d_in[17];

  bf16* Qws  = (bf16*)d_ws;                     // (8,8,1024,128)  16 MB
  bf16* Kws  = Qws  + (size_t)8 * 1024 * 1024;  // (8,8,1024,128)  16 MB
  bf16* Vtws = Kws  + (size_t)8 * 1024 * 1024;  // (8,8,64,1024)    8 MB
  bf16* Ows  = Vtws + (size_t)4 * 1024 * 1024;  // (8192,512)       8 MB

  proj_gemm<<<dim3(1280), dim3(256), 0, stream>>>(
      qc, qp, kc, kp, vin, Wqc, bqc, Wqp, bqp, Wkc, bkc, Wkp, bkp, Wv, bv,
      Qws, Kws, Vtws);
  attn_fwd<<<dim3(1024), dim3(256), 0, stream>>>(Qws, Kws, Vtws, mask, Ows);
  out_gemm<<<dim3(256), dim3(256), 0, stream>>>(Ows, Wo, bo, (float*)d_out);
}

// Round 4
// 211.953 us; speedup vs baseline: 1.4470x; 1.3749x over previous
//
#include <hip/hip_runtime.h>
#include <hip/hip_bf16.h>

typedef __bf16 bf16;
typedef __bf16 bf16x8 __attribute__((ext_vector_type(8)));
typedef float  f32x4  __attribute__((ext_vector_type(4)));

#define LOG2E        1.4426950408889634f
#define QSCALE_LOG2E 0.18033688011112043f   /* log2(e)/8 */
#define DEFER_THR    20.0f                  /* rescale only if logit2 > m+20 */

// async global->LDS, 16B per lane; LDS dest = uniform base + lane*16
#define GLDS(g, l)                                                        \
  __builtin_amdgcn_global_load_lds(                                       \
      (const __attribute__((address_space(1))) void*)(g),                 \
      (__attribute__((address_space(3))) void*)(l), 16, 0, 0)

// ---------------------------------------------------------------------------
// LDS staging helpers: [128 rows][64 k] bf16 tile, 128B rows, 16B chunks
// XOR-swizzled: chunk' = chunk ^ (row & 7). Write/read use the same involution.
// ---------------------------------------------------------------------------
__device__ __forceinline__ void stage_f32_tile(const float* __restrict__ src, int ld,
                                               char* dst, int tid) {
  #pragma unroll
  for (int t = 0; t < 8; ++t) {
    int c8  = tid + t * 256;          // 2048 8-byte units = 128 rows * 16
    int row = c8 >> 4;
    int h8  = c8 & 15;
    const f32x4 v = *reinterpret_cast<const f32x4*>(src + row * ld + h8 * 4);
    union { bf16 h[4]; unsigned long long u; } pk;
    pk.h[0] = (bf16)v[0]; pk.h[1] = (bf16)v[1];
    pk.h[2] = (bf16)v[2]; pk.h[3] = (bf16)v[3];
    int byte = (row << 7) + ((((h8 >> 1) ^ (row & 7)) << 4) | ((h8 & 1) << 3));
    *reinterpret_cast<unsigned long long*>(dst + byte) = pk.u;
  }
}

__device__ __forceinline__ void stage_bf16_tile(const bf16* __restrict__ src, int ld,
                                                char* dst, int tid) {
  #pragma unroll
  for (int t = 0; t < 4; ++t) {
    int c   = tid + t * 256;          // 1024 16-byte chunks = 128 rows * 8
    int row = c >> 3;
    int ck  = c & 7;
    const bf16x8 v = *reinterpret_cast<const bf16x8*>(src + row * ld + ck * 8);
    int byte = (row << 7) + (((ck ^ (row & 7)) << 4));
    *reinterpret_cast<bf16x8*>(dst + byte) = v;
  }
}

// ---------------------------------------------------------------------------
// Kernel 1: all 5 projection GEMMs. grid = 5 * 64 * 4 = 1280 blocks, 256 thr.
// ---------------------------------------------------------------------------
__global__ __launch_bounds__(256) void proj_gemm(
    const float* __restrict__ qc, const float* __restrict__ qp,
    const float* __restrict__ kc, const float* __restrict__ kp,
    const float* __restrict__ vin,
    const float* __restrict__ Wqc, const float* __restrict__ bqc,
    const float* __restrict__ Wqp, const float* __restrict__ bqp,
    const float* __restrict__ Wkc, const float* __restrict__ bkc,
    const float* __restrict__ Wkp, const float* __restrict__ bkp,
    const float* __restrict__ Wv,  const float* __restrict__ bv,
    bf16* __restrict__ Qws, bf16* __restrict__ Kws, bf16* __restrict__ Vtws) {
  __shared__ __align__(16) bf16 lA[128 * 64];
  __shared__ __align__(16) bf16 lB[128 * 64];
  char* lAb = (char*)lA;
  char* lBb = (char*)lB;

  const int bx = blockIdx.x;
  const int g  = bx >> 8;             // which of the 5 GEMMs
  const int mt = (bx & 255) >> 2;     // 64 M-tiles
  const int nt = bx & 3;              // 4 N-tiles

  const float *A, *W, *bias;
  if      (g == 0) { A = qc;  W = Wqc; bias = bqc; }
  else if (g == 1) { A = qp;  W = Wqp; bias = bqp; }
  else if (g == 2) { A = kc;  W = Wkc; bias = bkc; }
  else if (g == 3) { A = kp;  W = Wkp; bias = bkp; }
  else             { A = vin; W = Wv;  bias = bv;  }

  const int tid  = threadIdx.x;
  const int lane = tid & 63, wid = tid >> 6;
  const int wr = wid >> 1, wc = wid & 1;
  const int lrow = lane & 15, lgrp = lane >> 4;

  const float* Abase = A + (size_t)(mt * 128) * 512;
  const float* Wbase = W + (size_t)(nt * 128) * 512;

  const f32x4 fz = {0.f, 0.f, 0.f, 0.f};
  f32x4 acc[4][4];
  #pragma unroll
  for (int i = 0; i < 4; ++i)
    #pragma unroll
    for (int j = 0; j < 4; ++j) acc[i][j] = fz;

  for (int k0 = 0; k0 < 512; k0 += 64) {
    __syncthreads();
    stage_f32_tile(Abase + k0, 512, lAb, tid);
    stage_f32_tile(Wbase + k0, 512, lBb, tid);
    __syncthreads();
    #pragma unroll
    for (int kk = 0; kk < 2; ++kk) {
      bf16x8 af[4], bfr[4];
      #pragma unroll
      for (int mf = 0; mf < 4; ++mf) {
        int row  = wr * 64 + mf * 16 + lrow;
        int byte = (row << 7) + ((((kk << 2) | lgrp) ^ (row & 7)) << 4);
        af[mf] = *reinterpret_cast<const bf16x8*>(lAb + byte);
      }
      #pragma unroll
      for (int nf = 0; nf < 4; ++nf) {
        int row  = wc * 64 + nf * 16 + lrow;
        int byte = (row << 7) + ((((kk << 2) | lgrp) ^ (row & 7)) << 4);
        bfr[nf] = *reinterpret_cast<const bf16x8*>(lBb + byte);
      }
      #pragma unroll
      for (int mf = 0; mf < 4; ++mf)
        #pragma unroll
        for (int nf = 0; nf < 4; ++nf)
          acc[mf][nf] = __builtin_amdgcn_mfma_f32_16x16x32_bf16(
              af[mf], bfr[nf], acc[mf][nf], 0, 0, 0);
    }
  }

  float bcol[4];
  #pragma unroll
  for (int nf = 0; nf < 4; ++nf)
    bcol[nf] = bias[nt * 128 + wc * 64 + nf * 16 + lrow];

  #pragma unroll
  for (int mf = 0; mf < 4; ++mf) {
    #pragma unroll
    for (int nf = 0; nf < 4; ++nf) {
      #pragma unroll
      for (int r = 0; r < 4; ++r) {
        int grow = mt * 128 + wr * 64 + mf * 16 + lgrp * 4 + r;  // 0..8191
        int col  = nt * 128 + wc * 64 + nf * 16 + lrow;          // 0..511
        float vv = acc[mf][nf][r] + bcol[nf];
        bf16 hb  = (bf16)vv;
        int n = grow >> 10, tt = grow & 1023;
        if (g < 2) {
          int j = (g << 9) + col;     // 0..1023
          Qws[(size_t)((((n << 3) + (j >> 7)) << 10) | tt) * 128 + (j & 127)] = hb;
        } else if (g < 4) {
          int j = ((g - 2) << 9) + col;
          Kws[(size_t)((((n << 3) + (j >> 7)) << 10) | tt) * 128 + (j & 127)] = hb;
        } else {
          int h = col >> 6, d = col & 63;
          Vtws[(size_t)((((n << 3) + h) << 6) + d) * 1024 + tt] = hb;
        }
      }
    }
  }
}

// ---------------------------------------------------------------------------
// Kernel 2: flash attention with cooperative LDS staging of K/V.
// grid = 64 (n,h) * 16 q-tiles = 1024 blocks; 4 waves x 16 queries.
// Per 32-key step: K (8KB, XOR-swizzled via pre-swizzled global src) and
// V (4KB, linear) double-buffered via global_load_lds; fragments via
// ds_read_b128 (conflict-free); mask prefetched to registers; defer-max
// softmax; one __syncthreads per step (drains staging vmcnt).
// ---------------------------------------------------------------------------
__global__ __launch_bounds__(256) void attn_fwd(
    const bf16* __restrict__ Qws, const bf16* __restrict__ Kws,
    const bf16* __restrict__ Vtws, const float* __restrict__ mask,
    bf16* __restrict__ Ows) {
  __shared__ __align__(16) char Kl[2][8192];   // [buf][32 keys][16 chunks*16B]
  __shared__ __align__(16) char Vl[2][4096];   // [buf][64 d][32 s * 2B]
  __shared__ __align__(16) bf16 Pl[4][2][16][32];

  const int bx = blockIdx.x;
  const int nh = bx >> 4;
  const int qt = bx & 15;
  const int tid = threadIdx.x;
  const int lane = tid & 63, wid = tid >> 6;
  const int lrow = lane & 15, lgrp = lane >> 4;
  const int q0 = qt * 64 + wid * 16;

  // Q fragments (held for the whole loop)
  const bf16* Qb = Qws + ((size_t)(nh * 1024 + q0 + lrow)) * 128 + lgrp * 8;
  bf16x8 qf[4];
  #pragma unroll
  for (int kk = 0; kk < 4; ++kk)
    qf[kk] = *reinterpret_cast<const bf16x8*>(Qb + kk * 32);

  const float* Mb = mask + ((size_t)(nh * 1024 + q0 + lgrp * 4)) * 1024 + lrow;

  // staging source addresses (per-lane, pre-swizzled for K; m173 pattern)
  const int kc0 = wid * 128 + lane;            // chunk 0..511 (instr 0)
  const int kr0 = kc0 >> 4, kd0 = kc0 & 15;
  const bf16* Kg0 = Kws + ((size_t)(nh * 1024 + kr0)) * 128 + (kd0 ^ (kr0 & 7)) * 8;
  const int kc1 = kc0 + 64;                    // instr 1
  const int kr1 = kc1 >> 4, kd1 = kc1 & 15;
  const bf16* Kg1 = Kws + ((size_t)(nh * 1024 + kr1)) * 128 + (kd1 ^ (kr1 & 7)) * 8;
  const int vc  = wid * 64 + lane;             // chunk 0..255
  const int vr  = vc >> 2, vs = vc & 3;
  const bf16* Vg = Vtws + ((size_t)(nh * 64 + vr)) * 1024 + vs * 8;

  char* Pb0 = (char*)&Pl[wid][0][0][0];        // two 1KB per-wave P buffers

  const f32x4 fz = {0.f, 0.f, 0.f, 0.f};
  f32x4 oacc[4];
  #pragma unroll
  for (int dt = 0; dt < 4; ++dt) oacc[dt] = fz;
  float m2[4], lsum[4];
  #pragma unroll
  for (int r = 0; r < 4; ++r) { m2[r] = 0.f; lsum[r] = 0.f; }

  auto stageKV = [&](int buf, int s0) {
    GLDS(Kg0 + (size_t)s0 * 128, &Kl[buf][wid * 2048]);
    GLDS(Kg1 + (size_t)s0 * 128, &Kl[buf][wid * 2048 + 1024]);
    GLDS(Vg + s0,                &Vl[buf][wid * 1024]);
  };

  // one 32-key step: compute tile at s0 from LDS buf; prefetch mask for sp;
  // stage next K/V tile into buf^1 (unless last).
  auto step = [&](int s0, int buf, float (&MK)[8], float (&MN)[8],
                  int sp, bool pref) {
    if (pref) stageKV(buf ^ 1, s0 + 32);
    if (sp >= 0) {
      #pragma unroll
      for (int r = 0; r < 4; ++r) {
        MN[r]     = Mb[(size_t)r * 1024 + sp];
        MN[4 + r] = Mb[(size_t)r * 1024 + sp + 16];
      }
    }

    // ---- fragments from LDS ----
    const char* Kb = &Kl[buf][0];
    const char* Vb = &Vl[buf][0];
    bf16x8 kf0[4], kf1[4], vf[4];
    #pragma unroll
    for (int kk = 0; kk < 4; ++kk) {
      int ch = ((kk << 2) | lgrp) ^ (lrow & 7);
      kf0[kk] = *reinterpret_cast<const bf16x8*>(Kb + lrow * 256 + ch * 16);
      kf1[kk] = *reinterpret_cast<const bf16x8*>(Kb + (16 + lrow) * 256 + ch * 16);
    }
    #pragma unroll
    for (int dt = 0; dt < 4; ++dt)
      vf[dt] = *reinterpret_cast<const bf16x8*>(Vb + (dt * 16 + lrow) * 64 + lgrp * 16);

    // ---- QK^T: two 16-key column tiles ----
    f32x4 sc0 = fz, sc1 = fz;
    #pragma unroll
    for (int kk = 0; kk < 4; ++kk)
      sc0 = __builtin_amdgcn_mfma_f32_16x16x32_bf16(qf[kk], kf0[kk], sc0, 0, 0, 0);
    #pragma unroll
    for (int kk = 0; kk < 4; ++kk)
      sc1 = __builtin_amdgcn_mfma_f32_16x16x32_bf16(qf[kk], kf1[kk], sc1, 0, 0, 0);

    // logits (base-2): a = s * log2e/8 + mask * log2e
    float a0r[4], a1r[4];
    bool ok = true;
    #pragma unroll
    for (int r = 0; r < 4; ++r) {
      a0r[r] = fmaf(sc0[r], QSCALE_LOG2E, MK[r] * LOG2E);
      a1r[r] = fmaf(sc1[r], QSCALE_LOG2E, MK[4 + r] * LOG2E);
      ok &= (fmaxf(a0r[r], a1r[r]) <= m2[r] + DEFER_THR);
    }
    // defer-max: rescale only when some logit exceeds m+THR (~never here)
    if (__builtin_expect(!__all(ok), 0)) {
      #pragma unroll
      for (int r = 0; r < 4; ++r) {
        float tv = fmaxf(a0r[r], a1r[r]);
        tv = fmaxf(tv, __shfl_xor(tv, 1));
        tv = fmaxf(tv, __shfl_xor(tv, 2));
        tv = fmaxf(tv, __shfl_xor(tv, 4));
        tv = fmaxf(tv, __shfl_xor(tv, 8));
        float mn = fmaxf(m2[r], tv);
        float corr = exp2f(m2[r] - mn);
        m2[r] = mn;
        lsum[r] *= corr;
        #pragma unroll
        for (int dt = 0; dt < 4; ++dt) oacc[dt][r] *= corr;
      }
    }
    float p0[4], p1[4];
    #pragma unroll
    for (int r = 0; r < 4; ++r) {
      float e0 = exp2f(a0r[r] - m2[r]);
      float e1 = exp2f(a1r[r] - m2[r]);
      p0[r] = e0; p1[r] = e1;
      lsum[r] += e0 + e1;          // per-lane partial; reduced once at the end
    }

    // P (D-layout) -> LDS row-major [16 q][32 s] bf16  (double-buffered)
    char* Pb = Pb0 + ((s0 & 32) << 5);   // alternates 0 / 1KB
    #pragma unroll
    for (int r = 0; r < 4; ++r) {
      int rowb = (lgrp * 4 + r) * 64;
      *reinterpret_cast<bf16*>(Pb + rowb + lrow * 2)      = (bf16)p0[r];
      *reinterpret_cast<bf16*>(Pb + rowb + 32 + lrow * 2) = (bf16)p1[r];
    }
    __builtin_amdgcn_wave_barrier();
    __builtin_amdgcn_sched_barrier(0);
    bf16x8 pf = *reinterpret_cast<const bf16x8*>(Pb + lrow * 64 + lgrp * 16);

    // PV: O[16q x 64d] += P[16x32] * V[32 x 64]
    #pragma unroll
    for (int dt = 0; dt < 4; ++dt)
      oacc[dt] = __builtin_amdgcn_mfma_f32_16x16x32_bf16(pf, vf[dt], oacc[dt], 0, 0, 0);

    __syncthreads();   // drains staging vmcnt + all LDS reads of buf
  };

  float mA[8], mB[8];
  // prologue: stage tile 0, prefetch mask 0
  stageKV(0, 0);
  #pragma unroll
  for (int r = 0; r < 4; ++r) {
    mA[r]     = Mb[(size_t)r * 1024];
    mA[4 + r] = Mb[(size_t)r * 1024 + 16];
  }
  __syncthreads();

  for (int tt = 0; tt < 16; ++tt) {
    int s0 = tt * 64;
    step(s0,      0, mA, mB, s0 + 32, true);
    step(s0 + 32, 1, mB, mA, (tt < 15) ? (s0 + 64) : -1, tt < 15);
  }

  // final denominator reduce (deferred from the loop)
  #pragma unroll
  for (int r = 0; r < 4; ++r) {
    float ss = lsum[r];
    ss += __shfl_xor(ss, 1);
    ss += __shfl_xor(ss, 2);
    ss += __shfl_xor(ss, 4);
    ss += __shfl_xor(ss, 8);
    lsum[r] = 1.0f / ss;
  }

  const int n = nh >> 3, h = nh & 7;
  bf16* Ob = Ows + ((size_t)(n * 1024 + q0 + lgrp * 4)) * 512 + h * 64 + lrow;
  #pragma unroll
  for (int dt = 0; dt < 4; ++dt)
    #pragma unroll
    for (int r = 0; r < 4; ++r)
      Ob[(size_t)r * 512 + dt * 16] = (bf16)(oacc[dt][r] * lsum[r]);
}

// ---------------------------------------------------------------------------
// Kernel 3: output projection. grid = 64 * 4 = 256 blocks.
// ---------------------------------------------------------------------------
__global__ __launch_bounds__(256) void out_gemm(
    const bf16* __restrict__ Ows, const float* __restrict__ Wo,
    const float* __restrict__ bo, float* __restrict__ out) {
  __shared__ __align__(16) bf16 lA[128 * 64];
  __shared__ __align__(16) bf16 lB[128 * 64];
  char* lAb = (char*)lA;
  char* lBb = (char*)lB;

  const int bx = blockIdx.x;
  const int mt = bx >> 2;
  const int nt = bx & 3;
  const int tid = threadIdx.x;
  const int lane = tid & 63, wid = tid >> 6;
  const int wr = wid >> 1, wc = wid & 1;
  const int lrow = lane & 15, lgrp = lane >> 4;

  const bf16*  Abase = Ows + (size_t)(mt * 128) * 512;
  const float* Wbase = Wo  + (size_t)(nt * 128) * 512;

  const f32x4 fz = {0.f, 0.f, 0.f, 0.f};
  f32x4 acc[4][4];
  #pragma unroll
  for (int i = 0; i < 4; ++i)
    #pragma unroll
    for (int j = 0; j < 4; ++j) acc[i][j] = fz;

  for (int k0 = 0; k0 < 512; k0 += 64) {
    __syncthreads();
    stage_bf16_tile(Abase + k0, 512, lAb, tid);
    stage_f32_tile(Wbase + k0, 512, lBb, tid);
    __syncthreads();
    #pragma unroll
    for (int kk = 0; kk < 2; ++kk) {
      bf16x8 af[4], bfr[4];
      #pragma unroll
      for (int mf = 0; mf < 4; ++mf) {
        int row  = wr * 64 + mf * 16 + lrow;
        int byte = (row << 7) + ((((kk << 2) | lgrp) ^ (row & 7)) << 4);
        af[mf] = *reinterpret_cast<const bf16x8*>(lAb + byte);
      }
      #pragma unroll
      for (int nf = 0; nf < 4; ++nf) {
        int row  = wc * 64 + nf * 16 + lrow;
        int byte = (row << 7) + ((((kk << 2) | lgrp) ^ (row & 7)) << 4);
        bfr[nf] = *reinterpret_cast<const bf16x8*>(lBb + byte);
      }
      #pragma unroll
      for (int mf = 0; mf < 4; ++mf)
        #pragma unroll
        for (int nf = 0; nf < 4; ++nf)
          acc[mf][nf] = __builtin_amdgcn_mfma_f32_16x16x32_bf16(
              af[mf], bfr[nf], acc[mf][nf], 0, 0, 0);
    }
  }

  float bcol[4];
  #pragma unroll
  for (int nf = 0; nf < 4; ++nf)
    bcol[nf] = bo[nt * 128 + wc * 64 + nf * 16 + lrow];

  #pragma unroll
  for (int mf = 0; mf < 4; ++mf) {
    #pragma unroll
    for (int nf = 0; nf < 4; ++nf) {
      #pragma unroll
      for (int r = 0; r < 4; ++r) {
        int grow = mt * 128 + wr * 64 + mf * 16 + lgrp * 4 + r;
        int col  = nt * 128 + wc * 64 + nf * 16 + lrow;
        out[(size_t)grow * 512 + col] = acc[mf][nf][r] + bcol[nf];
      }
    }
  }
}

// ---------------------------------------------------------------------------
extern "C" void kernel_launch(void* const* d_in, const int* in_sizes, int n_in,
                              void* d_out, int out_size, void* d_ws, size_t ws_size,
                              hipStream_t stream) {
  const float* qc   = (const float*)d_in[0];
  const float* qp   = (const float*)d_in[1];
  const float* kc   = (const float*)d_in[2];
  const float* kp   = (const float*)d_in[3];
  const float* vin  = (const float*)d_in[4];
  const float* mask = (const float*)d_in[5];
  const float* Wqc  = (const float*)d_in[6];
  const float* bqc  = (const float*)d_in[7];
  const float* Wqp  = (const float*)d_in[8];
  const float* bqp  = (const float*)d_in[9];
  const float* Wkc  = (const float*)d_in[10];
  const float* bkc  = (const float*)d_in[11];
  const float* Wkp  = (const float*)d_in[12];
  const float* bkp  = (const float*)d_in[13];
  const float* Wv   = (const float*)d_in[14];
  const float* bv   = (const float*)d_in[15];
  const float* Wo   = (const float*)d_in[16];
  const float* bo   = (const float*)d_in[17];

  bf16* Qws  = (bf16*)d_ws;                     // (8,8,1024,128)  16 MB
  bf16* Kws  = Qws  + (size_t)8 * 1024 * 1024;  // (8,8,1024,128)  16 MB
  bf16* Vtws = Kws  + (size_t)8 * 1024 * 1024;  // (8,8,64,1024)    8 MB
  bf16* Ows  = Vtws + (size_t)4 * 1024 * 1024;  // (8192,512)       8 MB

  proj_gemm<<<dim3(1280), dim3(256), 0, stream>>>(
      qc, qp, kc, kp, vin, Wqc, bqc, Wqp, bqp, Wkc, bkc, Wkp, bkp, Wv, bv,
      Qws, Kws, Vtws);
  attn_fwd<<<dim3(1024), dim3(256), 0, stream>>>(Qws, Kws, Vtws, mask, Ows);
  out_gemm<<<dim3(256), dim3(256), 0, stream>>>(Ows, Wo, bo, (float*)d_out);
}

// Round 5
// 196.841 us; speedup vs baseline: 1.5581x; 1.0768x over previous
//
#include <hip/hip_runtime.h>
#include <hip/hip_bf16.h>

typedef __bf16 bf16;
typedef __bf16 bf16x8 __attribute__((ext_vector_type(8)));
typedef float  f32x4  __attribute__((ext_vector_type(4)));
typedef float  f32x2  __attribute__((ext_vector_type(2)));

#define LOG2E        1.4426950408889634f
#define QSCALE_LOG2E 0.18033688011112043f   /* log2(e)/8 */
#define DEFER_THR    20.0f                  /* rescale only if logit2 > m+20 */

// async global->LDS, 16B per lane; LDS dest = uniform base + lane*16
#define GLDS(g, l)                                                        \
  __builtin_amdgcn_global_load_lds(                                       \
      (const __attribute__((address_space(1))) void*)(g),                 \
      (__attribute__((address_space(3))) void*)(l), 16, 0, 0)

// counted-vmcnt barrier: keep newest N VMEM ops in flight across the barrier
#define VMCNT_BAR(n) do {                                                 \
  asm volatile("s_waitcnt vmcnt(" #n ")" ::: "memory");                   \
  __builtin_amdgcn_s_barrier();                                           \
  __builtin_amdgcn_sched_barrier(0);                                      \
} while (0)

// ---------------------------------------------------------------------------
// LDS staging helpers for the GEMMs (unchanged, known good)
// ---------------------------------------------------------------------------
__device__ __forceinline__ void stage_f32_tile(const float* __restrict__ src, int ld,
                                               char* dst, int tid) {
  #pragma unroll
  for (int t = 0; t < 8; ++t) {
    int c8  = tid + t * 256;
    int row = c8 >> 4;
    int h8  = c8 & 15;
    const f32x4 v = *reinterpret_cast<const f32x4*>(src + row * ld + h8 * 4);
    union { bf16 h[4]; unsigned long long u; } pk;
    pk.h[0] = (bf16)v[0]; pk.h[1] = (bf16)v[1];
    pk.h[2] = (bf16)v[2]; pk.h[3] = (bf16)v[3];
    int byte = (row << 7) + ((((h8 >> 1) ^ (row & 7)) << 4) | ((h8 & 1) << 3));
    *reinterpret_cast<unsigned long long*>(dst + byte) = pk.u;
  }
}

__device__ __forceinline__ void stage_bf16_tile(const bf16* __restrict__ src, int ld,
                                                char* dst, int tid) {
  #pragma unroll
  for (int t = 0; t < 4; ++t) {
    int c   = tid + t * 256;
    int row = c >> 3;
    int ck  = c & 7;
    const bf16x8 v = *reinterpret_cast<const bf16x8*>(src + row * ld + ck * 8);
    int byte = (row << 7) + (((ck ^ (row & 7)) << 4));
    *reinterpret_cast<bf16x8*>(dst + byte) = v;
  }
}

// ---------------------------------------------------------------------------
// Kernel 1: all 5 projection GEMMs. grid = 5 * 64 * 4 = 1280 blocks, 256 thr.
// ---------------------------------------------------------------------------
__global__ __launch_bounds__(256) void proj_gemm(
    const float* __restrict__ qc, const float* __restrict__ qp,
    const float* __restrict__ kc, const float* __restrict__ kp,
    const float* __restrict__ vin,
    const float* __restrict__ Wqc, const float* __restrict__ bqc,
    const float* __restrict__ Wqp, const float* __restrict__ bqp,
    const float* __restrict__ Wkc, const float* __restrict__ bkc,
    const float* __restrict__ Wkp, const float* __restrict__ bkp,
    const float* __restrict__ Wv,  const float* __restrict__ bv,
    bf16* __restrict__ Qws, bf16* __restrict__ Kws, bf16* __restrict__ Vtws) {
  __shared__ __align__(16) bf16 lA[128 * 64];
  __shared__ __align__(16) bf16 lB[128 * 64];
  char* lAb = (char*)lA;
  char* lBb = (char*)lB;

  const int bx = blockIdx.x;
  const int g  = bx >> 8;
  const int mt = (bx & 255) >> 2;
  const int nt = bx & 3;

  const float *A, *W, *bias;
  if      (g == 0) { A = qc;  W = Wqc; bias = bqc; }
  else if (g == 1) { A = qp;  W = Wqp; bias = bqp; }
  else if (g == 2) { A = kc;  W = Wkc; bias = bkc; }
  else if (g == 3) { A = kp;  W = Wkp; bias = bkp; }
  else             { A = vin; W = Wv;  bias = bv;  }

  const int tid  = threadIdx.x;
  const int lane = tid & 63, wid = tid >> 6;
  const int wr = wid >> 1, wc = wid & 1;
  const int lrow = lane & 15, lgrp = lane >> 4;

  const float* Abase = A + (size_t)(mt * 128) * 512;
  const float* Wbase = W + (size_t)(nt * 128) * 512;

  const f32x4 fz = {0.f, 0.f, 0.f, 0.f};
  f32x4 acc[4][4];
  #pragma unroll
  for (int i = 0; i < 4; ++i)
    #pragma unroll
    for (int j = 0; j < 4; ++j) acc[i][j] = fz;

  for (int k0 = 0; k0 < 512; k0 += 64) {
    __syncthreads();
    stage_f32_tile(Abase + k0, 512, lAb, tid);
    stage_f32_tile(Wbase + k0, 512, lBb, tid);
    __syncthreads();
    #pragma unroll
    for (int kk = 0; kk < 2; ++kk) {
      bf16x8 af[4], bfr[4];
      #pragma unroll
      for (int mf = 0; mf < 4; ++mf) {
        int row  = wr * 64 + mf * 16 + lrow;
        int byte = (row << 7) + ((((kk << 2) | lgrp) ^ (row & 7)) << 4);
        af[mf] = *reinterpret_cast<const bf16x8*>(lAb + byte);
      }
      #pragma unroll
      for (int nf = 0; nf < 4; ++nf) {
        int row  = wc * 64 + nf * 16 + lrow;
        int byte = (row << 7) + ((((kk << 2) | lgrp) ^ (row & 7)) << 4);
        bfr[nf] = *reinterpret_cast<const bf16x8*>(lBb + byte);
      }
      #pragma unroll
      for (int mf = 0; mf < 4; ++mf)
        #pragma unroll
        for (int nf = 0; nf < 4; ++nf)
          acc[mf][nf] = __builtin_amdgcn_mfma_f32_16x16x32_bf16(
              af[mf], bfr[nf], acc[mf][nf], 0, 0, 0);
    }
  }

  float bcol[4];
  #pragma unroll
  for (int nf = 0; nf < 4; ++nf)
    bcol[nf] = bias[nt * 128 + wc * 64 + nf * 16 + lrow];

  #pragma unroll
  for (int mf = 0; mf < 4; ++mf) {
    #pragma unroll
    for (int nf = 0; nf < 4; ++nf) {
      #pragma unroll
      for (int r = 0; r < 4; ++r) {
        int grow = mt * 128 + wr * 64 + mf * 16 + lgrp * 4 + r;
        int col  = nt * 128 + wc * 64 + nf * 16 + lrow;
        float vv = acc[mf][nf][r] + bcol[nf];
        bf16 hb  = (bf16)vv;
        int n = grow >> 10, tt = grow & 1023;
        if (g < 2) {
          int j = (g << 9) + col;
          Qws[(size_t)((((n << 3) + (j >> 7)) << 10) | tt) * 128 + (j & 127)] = hb;
        } else if (g < 4) {
          int j = ((g - 2) << 9) + col;
          Kws[(size_t)((((n << 3) + (j >> 7)) << 10) | tt) * 128 + (j & 127)] = hb;
        } else {
          int h = col >> 6, d = col & 63;
          Vtws[(size_t)((((n << 3) + h) << 6) + d) * 1024 + tt] = hb;
        }
      }
    }
  }
}

// ---------------------------------------------------------------------------
// Kernel 2: flash attention, deep-pipelined.
// grid = 64 (n,h) * 16 q-tiles = 1024 blocks; 4 waves x 16 queries.
// Triple-buffered K/V staged 2 tiles ahead via global_load_lds; mask prefetch
// depth 2 (float2 pairs, even/odd key tiling); raw s_barrier with counted
// vmcnt so prefetches survive the barrier; packed b32 P writes; defer-max.
// ---------------------------------------------------------------------------
__global__ __launch_bounds__(256) void attn_fwd(
    const bf16* __restrict__ Qws, const bf16* __restrict__ Kws,
    const bf16* __restrict__ Vtws, const float* __restrict__ mask,
    bf16* __restrict__ Ows) {
  __shared__ __align__(16) char Kl[3][8192];   // [buf][32 keys][16 ch * 16B]
  __shared__ __align__(16) char Vl[3][4096];   // [buf][64 d][32 s * 2B]
  __shared__ __align__(16) char Pl[4][1024];   // per-wave P [16 q][32 s]

  const int bx = blockIdx.x;
  const int nh = bx >> 4;
  const int qt = bx & 15;
  const int tid = threadIdx.x;
  const int lane = tid & 63, wid = tid >> 6;
  const int lrow = lane & 15, lgrp = lane >> 4;
  const int q0 = qt * 64 + wid * 16;

  // Q fragments (held for the whole loop)
  const bf16* Qb = Qws + ((size_t)(nh * 1024 + q0 + lrow)) * 128 + lgrp * 8;
  bf16x8 qf[4];
  #pragma unroll
  for (int kk = 0; kk < 4; ++kk)
    qf[kk] = *reinterpret_cast<const bf16x8*>(Qb + kk * 32);

  // mask base: lane (lgrp,r) -> q row, lrow -> key pair (2*lrow, 2*lrow+1)
  const float* Mb = mask + ((size_t)(nh * 1024 + q0 + lgrp * 4)) * 1024 + 2 * lrow;

  // staging source addresses (per-lane, pre-swizzled for K with (row>>1)&7)
  const int kc0 = wid * 128 + lane;
  const int kr0 = kc0 >> 4, kd0 = kc0 & 15;
  const bf16* Kg0 = Kws + ((size_t)(nh * 1024 + kr0)) * 128 + (kd0 ^ ((kr0 >> 1) & 7)) * 8;
  const int kc1 = kc0 + 64;
  const int kr1 = kc1 >> 4, kd1 = kc1 & 15;
  const bf16* Kg1 = Kws + ((size_t)(nh * 1024 + kr1)) * 128 + (kd1 ^ ((kr1 >> 1) & 7)) * 8;
  const int vc  = wid * 64 + lane;
  const int vr  = vc >> 2, vs = vc & 3;
  const bf16* Vg = Vtws + ((size_t)(nh * 64 + vr)) * 1024 + vs * 8;

  char* Pb = &Pl[wid][0];

  const f32x4 fz = {0.f, 0.f, 0.f, 0.f};
  f32x4 oacc[4];
  #pragma unroll
  for (int dt = 0; dt < 4; ++dt) oacc[dt] = fz;
  float m2[4], lsum[4];
  #pragma unroll
  for (int r = 0; r < 4; ++r) { m2[r] = 0.f; lsum[r] = 0.f; }

  auto stageKV = [&](char* Ksg, char* Vsg, int sN) {
    GLDS(Kg0 + (size_t)sN * 128, Ksg + wid * 2048);
    GLDS(Kg1 + (size_t)sN * 128, Ksg + wid * 2048 + 1024);
    GLDS(Vg + sN,                Vsg + wid * 1024);
  };

  // softmax + P + PV shared by main and tail steps
  auto compute = [&](const char* Kb, const char* Vb, f32x2 (&MK)[4]) {
    bf16x8 kf0[4], kf1[4], vf[4];
    #pragma unroll
    for (int kk = 0; kk < 4; ++kk) {
      int cb = ((((kk << 2) | lgrp) ^ (lrow & 7)) << 4);
      kf0[kk] = *reinterpret_cast<const bf16x8*>(Kb + lrow * 512 + cb);
      kf1[kk] = *reinterpret_cast<const bf16x8*>(Kb + lrow * 512 + 256 + cb);
    }
    #pragma unroll
    for (int dt = 0; dt < 4; ++dt)
      vf[dt] = *reinterpret_cast<const bf16x8*>(Vb + (dt * 16 + lrow) * 64 + lgrp * 16);

    f32x4 sc0 = fz, sc1 = fz;
    __builtin_amdgcn_s_setprio(1);
    #pragma unroll
    for (int kk = 0; kk < 4; ++kk)
      sc0 = __builtin_amdgcn_mfma_f32_16x16x32_bf16(qf[kk], kf0[kk], sc0, 0, 0, 0);
    #pragma unroll
    for (int kk = 0; kk < 4; ++kk)
      sc1 = __builtin_amdgcn_mfma_f32_16x16x32_bf16(qf[kk], kf1[kk], sc1, 0, 0, 0);
    __builtin_amdgcn_s_setprio(0);

    float a0r[4], a1r[4];
    bool ok = true;
    #pragma unroll
    for (int r = 0; r < 4; ++r) {
      f32x2 mv = MK[r];
      a0r[r] = fmaf(sc0[r], QSCALE_LOG2E, mv.x * LOG2E);
      a1r[r] = fmaf(sc1[r], QSCALE_LOG2E, mv.y * LOG2E);
      ok &= (fmaxf(a0r[r], a1r[r]) <= m2[r] + DEFER_THR);
    }
    if (__builtin_expect(!__all(ok), 0)) {
      #pragma unroll
      for (int r = 0; r < 4; ++r) {
        float tv = fmaxf(a0r[r], a1r[r]);
        tv = fmaxf(tv, __shfl_xor(tv, 1));
        tv = fmaxf(tv, __shfl_xor(tv, 2));
        tv = fmaxf(tv, __shfl_xor(tv, 4));
        tv = fmaxf(tv, __shfl_xor(tv, 8));
        float mn = fmaxf(m2[r], tv);
        float corr = exp2f(m2[r] - mn);
        m2[r] = mn;
        lsum[r] *= corr;
        #pragma unroll
        for (int dt = 0; dt < 4; ++dt) oacc[dt][r] *= corr;
      }
    }
    // P packed writes: pair (key 2*lrow, 2*lrow+1) -> one b32, chunk-XOR'd
    #pragma unroll
    for (int r = 0; r < 4; ++r) {
      float e0 = exp2f(a0r[r] - m2[r]);
      float e1 = exp2f(a1r[r] - m2[r]);
      lsum[r] += e0 + e1;
      union { bf16 h[2]; unsigned u; } pk;
      pk.h[0] = (bf16)e0; pk.h[1] = (bf16)e1;
      int row = lgrp * 4 + r;
      int byte = row * 64 + ((((lrow >> 2) ^ (row & 3)) << 4) | ((lrow & 3) << 2));
      *reinterpret_cast<unsigned*>(Pb + byte) = pk.u;
    }
    __builtin_amdgcn_wave_barrier();
    __builtin_amdgcn_sched_barrier(0);
    bf16x8 pf = *reinterpret_cast<const bf16x8*>(
        Pb + lrow * 64 + ((lgrp ^ (lrow & 3)) << 4));

    __builtin_amdgcn_s_setprio(1);
    #pragma unroll
    for (int dt = 0; dt < 4; ++dt)
      oacc[dt] = __builtin_amdgcn_mfma_f32_16x16x32_bf16(pf, vf[dt], oacc[dt], 0, 0, 0);
    __builtin_amdgcn_s_setprio(0);
  };

  // main step: stage tile sN into (Ksg,Vsg); compute current; reload MK for sN
  auto step_main = [&](const char* Kb, const char* Vb, char* Ksg, char* Vsg,
                       int sN, f32x2 (&MK)[4]) {
    stageKV(Ksg, Vsg, sN);
    f32x2 mnew[4];
    #pragma unroll
    for (int r = 0; r < 4; ++r)
      mnew[r] = *reinterpret_cast<const f32x2*>(Mb + (size_t)r * 1024 + sN);
    compute(Kb, Vb, MK);
    #pragma unroll
    for (int r = 0; r < 4; ++r) MK[r] = mnew[r];
  };

  // --- prologue: stage tiles 0,1; load mask sets for steps 0,1 ---
  char *k0 = &Kl[0][0], *k1 = &Kl[1][0], *k2 = &Kl[2][0];
  char *v0 = &Vl[0][0], *v1 = &Vl[1][0], *v2 = &Vl[2][0];
  char *kc_ = k0, *kn_ = k1, *kf_ = k2;
  char *vc_ = v0, *vn_ = v1, *vf_ = v2;

  stageKV(kc_, vc_, 0);
  stageKV(kn_, vn_, 32);
  f32x2 mX[4], mY[4];
  #pragma unroll
  for (int r = 0; r < 4; ++r) {
    mX[r] = *reinterpret_cast<const f32x2*>(Mb + (size_t)r * 1024);
    mY[r] = *reinterpret_cast<const f32x2*>(Mb + (size_t)r * 1024 + 32);
  }
  VMCNT_BAR(8);   // drain the 6 staging loads; keep the 8 mask loads in flight

  // --- main loop: steps t=0..29, two per iteration ---
  for (int tt = 0; tt < 15; ++tt) {
    int s0 = tt * 64;
    step_main(kc_, vc_, kf_, vf_, s0 + 64, mX);   // t = 2tt,   stage t+2
    VMCNT_BAR(11);
    step_main(kn_, vn_, kc_, vc_, s0 + 96, mY);   // t = 2tt+1, stage t+3
    VMCNT_BAR(11);
    char* t1 = kc_; kc_ = kf_; kf_ = kn_; kn_ = t1;
    char* t2 = vc_; vc_ = vf_; vf_ = vn_; vn_ = t2;
  }

  // --- tail: steps 30, 31 (no more prefetch) ---
  compute(kc_, vc_, mX);
  VMCNT_BAR(4);
  compute(kn_, vn_, mY);

  // final denominator reduce (deferred from the loop)
  #pragma unroll
  for (int r = 0; r < 4; ++r) {
    float ss = lsum[r];
    ss += __shfl_xor(ss, 1);
    ss += __shfl_xor(ss, 2);
    ss += __shfl_xor(ss, 4);
    ss += __shfl_xor(ss, 8);
    lsum[r] = 1.0f / ss;
  }

  const int n = nh >> 3, h = nh & 7;
  bf16* Ob = Ows + ((size_t)(n * 1024 + q0 + lgrp * 4)) * 512 + h * 64 + lrow;
  #pragma unroll
  for (int dt = 0; dt < 4; ++dt)
    #pragma unroll
    for (int r = 0; r < 4; ++r)
      Ob[(size_t)r * 512 + dt * 16] = (bf16)(oacc[dt][r] * lsum[r]);
}

// ---------------------------------------------------------------------------
// Kernel 3: output projection. grid = 64 * 4 = 256 blocks.
// ---------------------------------------------------------------------------
__global__ __launch_bounds__(256) void out_gemm(
    const bf16* __restrict__ Ows, const float* __restrict__ Wo,
    const float* __restrict__ bo, float* __restrict__ out) {
  __shared__ __align__(16) bf16 lA[128 * 64];
  __shared__ __align__(16) bf16 lB[128 * 64];
  char* lAb = (char*)lA;
  char* lBb = (char*)lB;

  const int bx = blockIdx.x;
  const int mt = bx >> 2;
  const int nt = bx & 3;
  const int tid = threadIdx.x;
  const int lane = tid & 63, wid = tid >> 6;
  const int wr = wid >> 1, wc = wid & 1;
  const int lrow = lane & 15, lgrp = lane >> 4;

  const bf16*  Abase = Ows + (size_t)(mt * 128) * 512;
  const float* Wbase = Wo  + (size_t)(nt * 128) * 512;

  const f32x4 fz = {0.f, 0.f, 0.f, 0.f};
  f32x4 acc[4][4];
  #pragma unroll
  for (int i = 0; i < 4; ++i)
    #pragma unroll
    for (int j = 0; j < 4; ++j) acc[i][j] = fz;

  for (int k0 = 0; k0 < 512; k0 += 64) {
    __syncthreads();
    stage_bf16_tile(Abase + k0, 512, lAb, tid);
    stage_f32_tile(Wbase + k0, 512, lBb, tid);
    __syncthreads();
    #pragma unroll
    for (int kk = 0; kk < 2; ++kk) {
      bf16x8 af[4], bfr[4];
      #pragma unroll
      for (int mf = 0; mf < 4; ++mf) {
        int row  = wr * 64 + mf * 16 + lrow;
        int byte = (row << 7) + ((((kk << 2) | lgrp) ^ (row & 7)) << 4);
        af[mf] = *reinterpret_cast<const bf16x8*>(lAb + byte);
      }
      #pragma unroll
      for (int nf = 0; nf < 4; ++nf) {
        int row  = wc * 64 + nf * 16 + lrow;
        int byte = (row << 7) + ((((kk << 2) | lgrp) ^ (row & 7)) << 4);
        bfr[nf] = *reinterpret_cast<const bf16x8*>(lBb + byte);
      }
      #pragma unroll
      for (int mf = 0; mf < 4; ++mf)
        #pragma unroll
        for (int nf = 0; nf < 4; ++nf)
          acc[mf][nf] = __builtin_amdgcn_mfma_f32_16x16x32_bf16(
              af[mf], bfr[nf], acc[mf][nf], 0, 0, 0);
    }
  }

  float bcol[4];
  #pragma unroll
  for (int nf = 0; nf < 4; ++nf)
    bcol[nf] = bo[nt * 128 + wc * 64 + nf * 16 + lrow];

  #pragma unroll
  for (int mf = 0; mf < 4; ++mf) {
    #pragma unroll
    for (int nf = 0; nf < 4; ++nf) {
      #pragma unroll
      for (int r = 0; r < 4; ++r) {
        int grow = mt * 128 + wr * 64 + mf * 16 + lgrp * 4 + r;
        int col  = nt * 128 + wc * 64 + nf * 16 + lrow;
        out[(size_t)grow * 512 + col] = acc[mf][nf][r] + bcol[nf];
      }
    }
  }
}

// ---------------------------------------------------------------------------
extern "C" void kernel_launch(void* const* d_in, const int* in_sizes, int n_in,
                              void* d_out, int out_size, void* d_ws, size_t ws_size,
                              hipStream_t stream) {
  const float* qc   = (const float*)d_in[0];
  const float* qp   = (const float*)d_in[1];
  const float* kc   = (const float*)d_in[2];
  const float* kp   = (const float*)d_in[3];
  const float* vin  = (const float*)d_in[4];
  const float* mask = (const float*)d_in[5];
  const float* Wqc  = (const float*)d_in[6];
  const float* bqc  = (const float*)d_in[7];
  const float* Wqp  = (const float*)d_in[8];
  const float* bqp  = (const float*)d_in[9];
  const float* Wkc  = (const float*)d_in[10];
  const float* bkc  = (const float*)d_in[11];
  const float* Wkp  = (const float*)d_in[12];
  const float* bkp  = (const float*)d_in[13];
  const float* Wv   = (const float*)d_in[14];
  const float* bv   = (const float*)d_in[15];
  const float* Wo   = (const float*)d_in[16];
  const float* bo   = (const float*)d_in[17];

  bf16* Qws  = (bf16*)d_ws;                     // (8,8,1024,128)  16 MB
  bf16* Kws  = Qws  + (size_t)8 * 1024 * 1024;  // (8,8,1024,128)  16 MB
  bf16* Vtws = Kws  + (size_t)8 * 1024 * 1024;  // (8,8,64,1024)    8 MB
  bf16* Ows  = Vtws + (size_t)4 * 1024 * 1024;  // (8192,512)       8 MB

  proj_gemm<<<dim3(1280), dim3(256), 0, stream>>>(
      qc, qp, kc, kp, vin, Wqc, bqc, Wqp, bqp, Wkc, bkc, Wkp, bkp, Wv, bv,
      Qws, Kws, Vtws);
  attn_fwd<<<dim3(1024), dim3(256), 0, stream>>>(Qws, Kws, Vtws, mask, Ows);
  out_gemm<<<dim3(256), dim3(256), 0, stream>>>(Ows, Wo, bo, (float*)d_out);
}